// Round 5
// baseline (487.455 us; speedup 1.0000x reference)
//
#include <hip/hip_runtime.h>
#include <math.h>
#include <stdint.h>

// ---------------------------------------------------------------------------
// DPPSearch: NB=16, NL=64, V=16384, VOCAB=32000, D=256, TOPK=16, NITER=8
// Exact JAX threefry PARTITIONABLE stream (default since jax 0.4.36):
//   split(key,n)[i] = full pair of tf(key; 0, i)
//   random_bits(key,32,shape)[j] = y0 ^ y1 of tf(key; hi(j), lo(j))  <-- XOR fold
// f32 LU det winner scan. Masked rows of the output need bit-exact `best`.
//
// R1: k_gram single-wave LU + transposed-LDS gram.
// R2: k_topk threshold-gather top-16; k_out float4.
// R3: virtual pivoting (no row swaps, parity sign), reg-cached search col.
// R4 post-mortem: VGPR_Count=52 proved km[] spilled to SCRATCH (unroll cap
//     left p runtime -> runtime indices, rule: runtime-indexed arrays go to
//     scratch). k_ce was LDS-pipe-bound (1024 broadcast ds_read_b128/wave).
// R5: k_gram: runtime p-loop (small code) + FIXED-bound unrolled c=0..63
//     elimination (compile-time indices -> true registers); curcol register
//     carries the search column (no km[p] runtime index); f=0 for inactive
//     lanes; dead-column writes provably never read (|f|<=1 -> bounded).
//     k_ce: e/h via block-uniform SCALAR loads (SMEM pipe, readfirstlane'd
//     rid) instead of LDS broadcast; 2 rows/block halves W1 L2 traffic.
//     All fma chains / pivot comparator / sdet order unchanged (bit-exact).
// ---------------------------------------------------------------------------

#define TINYF 1.17549435082228750797e-38f

// Km swizzled dword index: rows of 68 dwords; XOR c bits 2..4 by (r>>3)&7
#define KMX(r, c) (((r) * 68) + ((c) ^ ((((r) >> 3) & 7) << 2)))

struct Keys16 { uint32_t k[16]; };

__host__ __device__ inline void tf2x32(uint32_t k0, uint32_t k1,
                                       uint32_t x0, uint32_t x1,
                                       uint32_t* o0, uint32_t* o1) {
  uint32_t ks2 = k0 ^ k1 ^ 0x1BD11BDAu;
  uint32_t ks[3] = {k0, k1, ks2};
  uint32_t v0 = x0 + k0, v1 = x1 + k1;
  const int R0[4] = {13, 15, 26, 6};
  const int R1[4] = {17, 29, 16, 24};
#pragma unroll
  for (int g = 0; g < 5; ++g) {
    const int* RR = (g & 1) ? R1 : R0;
#pragma unroll
    for (int r = 0; r < 4; ++r) {
      v0 += v1;
      v1 = (v1 << RR[r]) | (v1 >> (32 - RR[r]));
      v1 ^= v0;
    }
    v0 += ks[(g + 1) % 3];
    v1 += ks[(g + 2) % 3] + (uint32_t)(g + 1);
  }
  *o0 = v0; *o1 = v1;
}

// f32 log emulated via f64 (<=1 ulp of numpy/XLA logf)
__device__ inline float logf_ref(float x) { return (float)log((double)x); }

__device__ inline unsigned long long u64max(unsigned long long a,
                                            unsigned long long b) {
  return (a > b) ? a : b;
}

// broadcast float from lane (uniform sgpr-resident) without LDS
__device__ inline float lane_bcast_f32(float v, int slane) {
  return __uint_as_float(
      (unsigned)__builtin_amdgcn_readlane(__float_as_int(v), slane));
}

// --------------------------- top-16 per row --------------------------------
__global__ __launch_bounds__(256) void k_topk(const float* __restrict__ probas,
                                              const int* __restrict__ mask,
                                              int* __restrict__ topk_idx,
                                              float* __restrict__ logits,
                                              float* __restrict__ S) {
  int row = blockIdx.x;          // b*64+l, 0..1023
  int t = threadIdx.x;
  const float* p = probas + (size_t)row * 16384;
  __shared__ unsigned long long lists[256][16];  // fallback scratch; cand alias
  __shared__ float swsum[4];
  __shared__ int lcnt;
  unsigned long long* cand = &lists[0][0];  // first 512 slots

  cand[t] = 0ull;
  cand[t + 256] = 0ull;
  if (t == 0) lcnt = 0;
  __syncthreads();

  const uint32_t TB = 0x3F7E0000u;  // ~0.984375; E[cnt] = 16384/128 = 128
  float sum = 0.f;
  const float4* p4 = (const float4*)p;
#pragma unroll 4
  for (int j = 0; j < 16; ++j) {
    float4 x = p4[t + j * 256];
    int v0 = (t + j * 256) * 4;
    uint32_t u0 = __float_as_uint(x.x), u1 = __float_as_uint(x.y);
    uint32_t u2 = __float_as_uint(x.z), u3 = __float_as_uint(x.w);
    sum += x.x; sum += x.y; sum += x.z; sum += x.w;
    uint32_t um = max(max(u0, u1), max(u2, u3));
    if (um >= TB) {  // rare: ~6% of lane-iterations
      if (u0 >= TB) { int s = atomicAdd(&lcnt, 1); if (s < 512)
          cand[s] = ((unsigned long long)u0 << 32) | (unsigned)(~(v0 + 0)); }
      if (u1 >= TB) { int s = atomicAdd(&lcnt, 1); if (s < 512)
          cand[s] = ((unsigned long long)u1 << 32) | (unsigned)(~(v0 + 1)); }
      if (u2 >= TB) { int s = atomicAdd(&lcnt, 1); if (s < 512)
          cand[s] = ((unsigned long long)u2 << 32) | (unsigned)(~(v0 + 2)); }
      if (u3 >= TB) { int s = atomicAdd(&lcnt, 1); if (s < 512)
          cand[s] = ((unsigned long long)u3 << 32) | (unsigned)(~(v0 + 3)); }
    }
  }
#pragma unroll
  for (int off = 32; off >= 1; off >>= 1) sum += __shfl_down(sum, off);
  if ((t & 63) == 0) swsum[t >> 6] = sum;
  __syncthreads();
  if (t == 0) S[row] = ((swsum[0] + swsum[1]) + swsum[2]) + swsum[3];

  int n = lcnt;
  if (n >= 16 && n <= 512) {
    // -------- selection: one wave, 16 rounds of argmax-and-remove --------
    if (t < 64) {
      unsigned long long c[8];
#pragma unroll
      for (int k = 0; k < 8; ++k) c[k] = cand[t + 64 * k];  // pad slots are 0
      unsigned long long win = 0ull;
#pragma unroll
      for (int r = 0; r < 16; ++r) {
        unsigned long long m = c[0];
#pragma unroll
        for (int k = 1; k < 8; ++k) m = u64max(m, c[k]);
#pragma unroll
        for (int off = 32; off >= 1; off >>= 1) {
          unsigned long long o = __shfl_xor(m, off);
          m = u64max(m, o);
        }
        if (t == r) win = m;   // r is a literal (unrolled)
#pragma unroll
        for (int k = 0; k < 8; ++k) if (c[k] == m) c[k] = 0ull;  // unique keys
      }
      if (t < 16) {
        int idx = (int)(~(unsigned)(win & 0xFFFFFFFFull));
        float val = __uint_as_float((unsigned)(win >> 32));
        topk_idx[row * 16 + t] = idx;
        // masked rows: topk_vals := 1.0 -> logit 0
        logits[row * 16 + t] = (mask[row] == 0) ? 0.0f : logf_ref(val);
      }
    }
    return;
  }

  // -------------------- fallback: original exact path ----------------------
  {
    unsigned long long loc[16];
#pragma unroll
    for (int q = 0; q < 16; ++q) loc[q] = 0ull;
    for (int j = 0; j < 64; ++j) {
      int v = t + j * 256;
      float x = p[v];
      unsigned long long key =
          ((unsigned long long)__float_as_uint(x) << 32) | (unsigned)(~v);
      if (key > loc[15]) {
        loc[15] = key;
#pragma unroll
        for (int q = 15; q > 0; --q) {
          if (loc[q] > loc[q - 1]) {
            unsigned long long tmp = loc[q]; loc[q] = loc[q - 1]; loc[q - 1] = tmp;
          }
        }
      }
    }
    __syncthreads();  // cand region about to be overwritten
#pragma unroll
    for (int q = 0; q < 16; ++q) lists[t][q] = loc[q];
    __syncthreads();
    for (int nl = 128; nl >= 1; nl >>= 1) {
      if (t < nl) {
        unsigned long long M[16];
        int ia = 0, ib = 0;
#pragma unroll
        for (int q = 0; q < 16; ++q) {
          unsigned long long av = lists[t][ia];
          unsigned long long bv = lists[t + nl][ib];
          if (av >= bv) { M[q] = av; ia++; } else { M[q] = bv; ib++; }
        }
#pragma unroll
        for (int q = 0; q < 16; ++q) lists[t][q] = M[q];
      }
      __syncthreads();
    }
    if (t < 16) {
      unsigned long long key = lists[0][t];
      int idx = (int)(~(unsigned)(key & 0xFFFFFFFFull));
      float val = __uint_as_float((unsigned)(key >> 32));
      topk_idx[row * 16 + t] = idx;
      logits[row * 16 + t] = (mask[row] == 0) ? 0.0f : logf_ref(val);
    }
  }
}

// ------------------------ gumbel categorical sampling ----------------------
__global__ __launch_bounds__(256) void k_sample(Keys16 keys,
                                                const int* __restrict__ mask,
                                                const int* __restrict__ topk_idx,
                                                const float* __restrict__ logits,
                                                int* __restrict__ samples,
                                                int* __restrict__ choice) {
  int tid = blockIdx.x * 256 + threadIdx.x;  // 0..8191 = i*1024 + b*64 + l
  int i = tid >> 10;
  int rbl = tid & 1023;
  int b = rbl >> 6;
  int l = rbl & 63;
  uint32_t k0 = keys.k[2 * i], k1 = keys.k[2 * i + 1];
  int sl = 0;
  for (int m = 0; m < 64; ++m) sl += mask[b * 64 + m];
  float bestv = 0.f; int bestk = 0;
#pragma unroll
  for (int k = 0; k < 16; ++k) {
    uint32_t j = (uint32_t)((b * 64 + l) * 16 + k);  // flat idx in (16,64,16)
    uint32_t y0, y1;
    tf2x32(k0, k1, 0u, j, &y0, &y1);
    uint32_t bits = y0 ^ y1;  // 32-bit path: convert_element_type(bits1 ^ bits2)
    float f = __uint_as_float((bits >> 9) | 0x3f800000u) - 1.0f;
    float u = fmaxf(TINYF, f * 1.0f + TINYF);     // uniform(tiny, 1)
    float t1 = logf_ref(u);
    float g = -logf_ref(-t1);                      // gumbel
    float sv = g + logits[rbl * 16 + k];
    if (k == 0 || sv > bestv) { bestv = sv; bestk = k; }  // first-max
  }
  int ce = (l == sl - 1) ? 0 : bestk;  // one_hot: last valid pos -> MAP (=top1)
  choice[tid] = ce;
  samples[tid] = topk_idx[rbl * 16 + ce];
}

// ---- Eall[row,k,:] = relu(mk*(emb[bv[topk[row,k]]]@W1a) + h@W1b + b1) -----
// R5: 2 rows per block; e and h read via block-UNIFORM scalar loads (SMEM
// pipe) instead of LDS broadcast. Same fma chains as old k_h1/k_c per
// output (per-acc j-order unchanged -> bit-exact). Masked rows: hl[j] =
// h*0 = +-0 and the old chain provably yields acch == +0.0, so acch := 0.
__global__ __launch_bounds__(256) void k_ce(const int* __restrict__ topk_idx,
                                            const int* __restrict__ batch_vocab,
                                            const float* __restrict__ emb,
                                            const float* __restrict__ W1,
                                            const float* __restrict__ h_d,
                                            const float* __restrict__ b1,
                                            const int* __restrict__ mask,
                                            float* __restrict__ Eall) {
  int row0 = blockIdx.x * 2;  // two rows per block
  int t = threadIdx.x;        // d (output column)
  // block-uniform embedding row ids (SGPR via readfirstlane)
  int rid[2][16];
  int mk01[2];
#pragma unroll
  for (int r = 0; r < 2; ++r) {
    mk01[r] = __builtin_amdgcn_readfirstlane(mask[row0 + r]);
#pragma unroll
    for (int k = 0; k < 16; ++k) {
      int ti = topk_idx[(row0 + r) * 16 + k];  // uniform address -> s_load
      rid[r][k] = __builtin_amdgcn_readfirstlane(batch_vocab[ti]);
    }
  }
  // H1 part (identical chain to old k_h1 for mask==1; +0.0 for mask==0)
  float acch[2] = {0.f, 0.f};
  for (int j0 = 0; j0 < 256; j0 += 4) {
    float w0 = W1[(256 + j0 + 0) * 256 + t];
    float w1 = W1[(256 + j0 + 1) * 256 + t];
    float w2 = W1[(256 + j0 + 2) * 256 + t];
    float w3 = W1[(256 + j0 + 3) * 256 + t];
#pragma unroll
    for (int r = 0; r < 2; ++r) {
      float4 hv = *(const float4*)&h_d[(size_t)(row0 + r) * 256 + j0];  // uniform
      acch[r] = fmaf(hv.x, w0, acch[r]);
      acch[r] = fmaf(hv.y, w1, acch[r]);
      acch[r] = fmaf(hv.z, w2, acch[r]);
      acch[r] = fmaf(hv.w, w3, acch[r]);
    }
  }
#pragma unroll
  for (int r = 0; r < 2; ++r)
    if (mk01[r] == 0) acch[r] = 0.0f;  // == old chain's exact +0.0 result
  // C part (identical chain to old k_c per acc[r][k])
  float acc[2][16];
#pragma unroll
  for (int r = 0; r < 2; ++r)
#pragma unroll
    for (int k = 0; k < 16; ++k) acc[r][k] = 0.f;
  for (int j0 = 0; j0 < 256; j0 += 4) {
    float w0 = W1[(j0 + 0) * 256 + t];
    float w1 = W1[(j0 + 1) * 256 + t];
    float w2 = W1[(j0 + 2) * 256 + t];
    float w3 = W1[(j0 + 3) * 256 + t];
#pragma unroll
    for (int r = 0; r < 2; ++r) {
#pragma unroll
      for (int k = 0; k < 16; ++k) {
        // uniform scalar load (SMEM): same values as old LDS e[k][j0..3]
        float4 ev = *(const float4*)&emb[(size_t)rid[r][k] * 256 + j0];
        acc[r][k] = fmaf(ev.x, w0, acc[r][k]);
        acc[r][k] = fmaf(ev.y, w1, acc[r][k]);
        acc[r][k] = fmaf(ev.z, w2, acc[r][k]);
        acc[r][k] = fmaf(ev.w, w3, acc[r][k]);
      }
    }
  }
  float b1v = b1[t];
#pragma unroll
  for (int r = 0; r < 2; ++r) {
    float mkf = (float)mk01[r];
#pragma unroll
    for (int k = 0; k < 16; ++k) {
      float val = fmaf(mkf, acc[r][k], acch[r]) + b1v;
      Eall[((size_t)(row0 + r) * 16 + k) * 256 + t] = fmaxf(val, 0.0f);
    }
  }
}

// --------- per (iter, batch): gather E rows, K=E E^T, det via LU -----------
// Gram: transposed LDS tile, ds_read_b128. LU: wave 0, matrix in TRUE
// registers: runtime p-loop (compact code) + fixed-bound unrolled c-loop
// (all km[] indices compile-time -> mem2reg). curcol register carries the
// search column. Dead columns (<p+1) may receive garbage (bounded: |f|<=1)
// but are never read. Inactive lanes use f=0 (adds +-0; only retired /
// masked rows, never read again). Values/order identical to serial LU.
__global__ __launch_bounds__(256, 1) void k_gram(const float* __restrict__ Eall,
                                                 const int* __restrict__ mask,
                                                 const int* __restrict__ choice,
                                                 float* __restrict__ scores) {
  int blk = blockIdx.x;  // i*16 + b
  int i = blk >> 4, b = blk & 15;
  int t = threadIdx.x;
  __shared__ __align__(16) float Ett[64][68];   // per-dt chunk of E^T
  __shared__ __align__(16) float KmF[64 * 68];  // XOR-swizzled (KMX)
  __shared__ int ch[64];
  int mskv = 0;
  if (t < 64) {
    ch[t] = choice[i * 1024 + b * 64 + t];
    mskv = mask[b * 64 + t];  // prefetch for LU
  }
  __syncthreads();
  int l = t & 63, wd = t >> 6;  // wd: which 16-d slab of the 64-d chunk
  const float* eptr =
      Eall + ((size_t)((b * 64 + l) * 16 + ch[l])) * 256 + wd * 16;
  float acc[16];
#pragma unroll
  for (int q = 0; q < 16; ++q) acc[q] = 0.f;
  int tx = t & 15, ty = t >> 4;
  for (int dt = 0; dt < 4; ++dt) {
    const float* src = eptr + dt * 64;
    float4 v0 = *(const float4*)(src + 0);
    float4 v1 = *(const float4*)(src + 4);
    float4 v2 = *(const float4*)(src + 8);
    float4 v3 = *(const float4*)(src + 12);
    int d0 = wd * 16;
    Ett[d0 +  0][l] = v0.x; Ett[d0 +  1][l] = v0.y;
    Ett[d0 +  2][l] = v0.z; Ett[d0 +  3][l] = v0.w;
    Ett[d0 +  4][l] = v1.x; Ett[d0 +  5][l] = v1.y;
    Ett[d0 +  6][l] = v1.z; Ett[d0 +  7][l] = v1.w;
    Ett[d0 +  8][l] = v2.x; Ett[d0 +  9][l] = v2.y;
    Ett[d0 + 10][l] = v2.z; Ett[d0 + 11][l] = v2.w;
    Ett[d0 + 12][l] = v3.x; Ett[d0 + 13][l] = v3.y;
    Ett[d0 + 14][l] = v3.z; Ett[d0 + 15][l] = v3.w;
    __syncthreads();
#pragma unroll 4
    for (int dd = 0; dd < 64; ++dd) {   // d ascending: same acc order as before
      float4 av4 = *(const float4*)&Ett[dd][tx * 4];
      float4 bv4 = *(const float4*)&Ett[dd][ty * 4];
      float avv[4] = {av4.x, av4.y, av4.z, av4.w};
      float bvv[4] = {bv4.x, bv4.y, bv4.z, bv4.w};
#pragma unroll
      for (int a2 = 0; a2 < 4; ++a2)
#pragma unroll
        for (int c2 = 0; c2 < 4; ++c2)
          acc[a2 * 4 + c2] = fmaf(avv[a2], bvv[c2], acc[a2 * 4 + c2]);
    }
    __syncthreads();
  }
#pragma unroll
  for (int a2 = 0; a2 < 4; ++a2)
#pragma unroll
    for (int c2 = 0; c2 < 4; ++c2)
      KmF[KMX(tx * 4 + a2, ty * 4 + c2)] = acc[a2 * 4 + c2];
  __syncthreads();
  if (t >= 64) return;  // waves 1-3 done; wave 0 runs the LU

  unsigned long long bal = __ballot(mskv != 0);
  int L = __popcll(bal);  // prefix mask => leading LxL block

  // lane t owns original row t in registers (all indices compile-time)
  float km[64];
#pragma unroll
  for (int c0 = 0; c0 < 64; c0 += 4) {
    float4 v = *(const float4*)&KmF[KMX(t, c0)];
    km[c0 + 0] = v.x; km[c0 + 1] = v.y; km[c0 + 2] = v.z; km[c0 + 3] = v.w;
  }

  float sdet = 1.f, ssign = 1.f;   // uniform across lanes
  int pos = t;                      // current position of original row t
  float curcol = km[0];             // this row's entry in search column 0

#pragma unroll 1
  for (int p = 0; p < L; ++p) {     // runtime loop: compact code, no spill
    // candidates: unretired rows (current positions p..L-1)
    bool cnd = (pos >= p) && (pos < L);
    unsigned lo = (((unsigned)(63 - pos)) << 6) | (unsigned)t;
    unsigned long long key =
        cnd ? ((((unsigned long long)__float_as_uint(fabsf(curcol))) << 32) | lo)
            : 0ull;
#pragma unroll
    for (int off = 32; off >= 1; off >>= 1) {
      unsigned long long o = __shfl_xor(key, off);
      if (o > key) key = o;
    }
    int lane_rb = (int)(key & 63u);            // original row idx of winner
    int pb = 63 - (int)((key >> 6) & 63u);     // winner's current position
    int srb = __builtin_amdgcn_readfirstlane(lane_rb);  // -> SGPR
    float kpp = lane_bcast_f32(curcol, srb);   // signed pivot value
    sdet *= kpp;                               // ascending product order
    if (pb != p) ssign = -ssign;               // ipiv parity == swap parity
    // virtual swap: displaced row -> pb, winner -> p (retired)
    int np = pos;
    if (pos == p) np = pb;
    if (t == lane_rb) np = p;
    pos = np;
    // eliminate current rows p+1..L-1; inactive lanes get f=0 (no-op +-0)
    bool active = (pos > p) && (pos < L);
    float f = (active && kpp != 0.f) ? (curcol / kpp) : 0.f;  // IEEE f32 div
    float nf = -f;
    float ncc = curcol;
    int pp1 = p + 1;
#pragma unroll
    for (int chk = 0; chk < 8; ++chk) {
      if (chk * 8 + 7 >= pp1) {     // uniform branch: skip all-dead chunks
#pragma unroll
        for (int cc = 0; cc < 8; ++cc) {
          const int c = chk * 8 + cc;              // compile-time index
          float pr = lane_bcast_f32(km[c], srb);   // pivot row entry (SGPR)
          float nv = fmaf(nf, pr, km[c]);
          km[c] = nv;
          ncc = (c == pp1) ? nv : ncc;  // capture next search column
        }
      }
    }
    curcol = ncc;
  }
  if (t == 0) scores[i * 16 + b] = sdet * ssign;
}

// ------------- diverse_proba (+ inlined improve/early-stop scan) -----------
__global__ __launch_bounds__(256) void k_out(const float* __restrict__ probas,
                                             const int* __restrict__ mask,
                                             const int* __restrict__ samples,
                                             const int* __restrict__ topk_idx,
                                             const float* __restrict__ scores,
                                             const float* __restrict__ S,
                                             float* __restrict__ out,
                                             float* __restrict__ out_ms) {
  int row = blockIdx.x;  // b*64+l
  int b = row >> 6;
  int t = threadIdx.x;
  __shared__ float ssc[128];
  if (t < 128) ssc[t] = scores[t];
  __syncthreads();
  // winner scan (== old k_select), unrolled -> compile-time reg indices
  float ms[16]; int w[16];
#pragma unroll
  for (int q = 0; q < 16; ++q) { ms[q] = -INFINITY; w[q] = -1; }
  int count = 0; bool stopped = false;
#pragma unroll
  for (int i = 0; i < 8; ++i) {
    bool any = false; bool imp[16];
#pragma unroll
    for (int q = 0; q < 16; ++q) {
      imp[q] = ssc[i * 16 + q] > ms[q];
      any = any || imp[q];
    }
    count = any ? 0 : (count + 1);
#pragma unroll
    for (int q = 0; q < 16; ++q) {
      if (imp[q] && !stopped) { ms[q] = ssc[i * 16 + q]; w[q] = i; }
    }
    stopped = stopped || ((!any) && (count >= 2));
  }
  if (row == 0 && t == 0) {
#pragma unroll
    for (int q = 0; q < 16; ++q) out_ms[q] = ms[q];  // max_score output
  }
  int wi = -1;
#pragma unroll
  for (int q = 0; q < 16; ++q) if (b == q) wi = w[q];  // const-index select

  int best = (wi >= 0) ? samples[wi * 1024 + row] : topk_idx[row * 16];
  const float* p = probas + (size_t)row * 16384;
  float* o = out + (size_t)row * 16384;
  float nm;
  if (mask[row] == 0) {
    nm = 1e-10f;  // matches ref bit-for-bit (the only rows that matter)
  } else {
    nm = 0.2f * S[row] + 0.6f * p[best];  // values ~6e-4, far below threshold
  }
  const float4* p4 = (const float4*)p;
  float4* o4 = (float4*)o;
  for (int f = t; f < 4096; f += 256) {
    float4 x = p4[f];
    int v0 = f << 2;
    float4 r;
    // per element: x * am / nm — identical ops/order to scalar version
    r.x = x.x * ((v0 + 0 == best) ? 0.8f : 0.2f) / nm;
    r.y = x.y * ((v0 + 1 == best) ? 0.8f : 0.2f) / nm;
    r.z = x.z * ((v0 + 2 == best) ? 0.8f : 0.2f) / nm;
    r.w = x.w * ((v0 + 3 == best) ? 0.8f : 0.2f) / nm;
    o4[f] = r;
  }
}

// ---------------------------------------------------------------------------
extern "C" void kernel_launch(void* const* d_in, const int* in_sizes, int n_in,
                              void* d_out, int out_size, void* d_ws, size_t ws_size,
                              hipStream_t stream) {
  const float* probas = (const float*)d_in[0];
  const float* h_d    = (const float*)d_in[1];
  const int*   mask   = (const int*)d_in[2];
  const int*   bvoc   = (const int*)d_in[3];
  const float* emb    = (const float*)d_in[4];
  const float* W1     = (const float*)d_in[5];
  const float* b1     = (const float*)d_in[6];
  float* out = (float*)d_out;

  // small scratch in ws (~200 KB)
  char* w = (char*)d_ws;
  int*   topk_idx = (int*)w;   w += 16384 * sizeof(int);
  float* logits   = (float*)w; w += 16384 * sizeof(float);
  float* S        = (float*)w; w += 1024 * sizeof(float);
  int*   samples  = (int*)w;   w += 8192 * sizeof(int);
  int*   choice   = (int*)w;   w += 8192 * sizeof(int);
  float* scores   = (float*)w; w += 128 * sizeof(float);

  // large scratch lives inside d_out (rewritten by k_out at the end):
  // Eall: 16*64*16*256 = 4,194,304 floats (= relu(mask*C + H1 + b1))
  float* Eall = out;

  // keys = jax.random.split(jax.random.key(42), 8) under PARTITIONABLE
  Keys16 keys;
  for (uint32_t i = 0; i < 8; ++i) {
    uint32_t a, bq;
    tf2x32(0u, 42u, 0u, i, &a, &bq);
    keys.k[2 * i] = a; keys.k[2 * i + 1] = bq;
  }

  k_topk<<<1024, 256, 0, stream>>>(probas, mask, topk_idx, logits, S);
  k_sample<<<32, 256, 0, stream>>>(keys, mask, topk_idx, logits, samples, choice);
  k_ce<<<512, 256, 0, stream>>>(topk_idx, bvoc, emb, W1, h_d, b1, mask, Eall);
  k_gram<<<128, 256, 0, stream>>>(Eall, mask, choice, scores);
  k_out<<<1024, 256, 0, stream>>>(probas, mask, samples, topk_idx, scores, S,
                                  out, out + 16777216);
}

// Round 6
// 297.869 us; speedup vs baseline: 1.6365x; 1.6365x over previous
//
#include <hip/hip_runtime.h>
#include <math.h>
#include <stdint.h>

// ---------------------------------------------------------------------------
// DPPSearch: NB=16, NL=64, V=16384, VOCAB=32000, D=256, TOPK=16, NITER=8
// Exact JAX threefry PARTITIONABLE stream (default since jax 0.4.36):
//   split(key,n)[i] = full pair of tf(key; 0, i)
//   random_bits(key,32,shape)[j] = y0 ^ y1 of tf(key; hi(j), lo(j))  <-- XOR fold
// f32 LU det winner scan. Masked rows of the output need bit-exact `best`.
//
// R1: k_gram single-wave LU + transposed-LDS gram.
// R2: k_topk threshold-gather top-16; k_out float4.
// R3: virtual pivoting (no row swaps, parity sign), reg-cached search col.
// R4: k_gram register-LU attempt (spilled: VGPR=52); k_ce LDS-broadcast 67us.
// R5: k_gram register-LU fixed (runtime p-loop + fixed unrolled c-loop);
//     k_ce scalar-load experiment REGRESSED (236us: lgkmcnt-serialized
//     s_loads, no pipelining) -> reverted.
// R6: k_ce back to R4 LDS-broadcast structure + CHOSEN-SLOT COMPACTION:
//     gram only reads k in union(choice_i) (<=8 of 16 per row; choice is
//     available pre-k_ce). Per-row bitmask mb; slot=popc(mb&((1<<k)-1));
//     k_ce computes 8 slots (pad = lowest set bit, never read). Halves
//     C-part fma, e-staging, emb fetch. Per-slot fma chains unchanged ->
//     bit-exact. k_gram maps ch->slot with the same mask.
// ---------------------------------------------------------------------------

#define TINYF 1.17549435082228750797e-38f

// Km swizzled dword index: rows of 68 dwords; XOR c bits 2..4 by (r>>3)&7
#define KMX(r, c) (((r) * 68) + ((c) ^ ((((r) >> 3) & 7) << 2)))

struct Keys16 { uint32_t k[16]; };

__host__ __device__ inline void tf2x32(uint32_t k0, uint32_t k1,
                                       uint32_t x0, uint32_t x1,
                                       uint32_t* o0, uint32_t* o1) {
  uint32_t ks2 = k0 ^ k1 ^ 0x1BD11BDAu;
  uint32_t ks[3] = {k0, k1, ks2};
  uint32_t v0 = x0 + k0, v1 = x1 + k1;
  const int R0[4] = {13, 15, 26, 6};
  const int R1[4] = {17, 29, 16, 24};
#pragma unroll
  for (int g = 0; g < 5; ++g) {
    const int* RR = (g & 1) ? R1 : R0;
#pragma unroll
    for (int r = 0; r < 4; ++r) {
      v0 += v1;
      v1 = (v1 << RR[r]) | (v1 >> (32 - RR[r]));
      v1 ^= v0;
    }
    v0 += ks[(g + 1) % 3];
    v1 += ks[(g + 2) % 3] + (uint32_t)(g + 1);
  }
  *o0 = v0; *o1 = v1;
}

// f32 log emulated via f64 (<=1 ulp of numpy/XLA logf)
__device__ inline float logf_ref(float x) { return (float)log((double)x); }

__device__ inline unsigned long long u64max(unsigned long long a,
                                            unsigned long long b) {
  return (a > b) ? a : b;
}

// broadcast float from lane (uniform sgpr-resident) without LDS
__device__ inline float lane_bcast_f32(float v, int slane) {
  return __uint_as_float(
      (unsigned)__builtin_amdgcn_readlane(__float_as_int(v), slane));
}

// --------------------------- top-16 per row --------------------------------
__global__ __launch_bounds__(256) void k_topk(const float* __restrict__ probas,
                                              const int* __restrict__ mask,
                                              int* __restrict__ topk_idx,
                                              float* __restrict__ logits,
                                              float* __restrict__ S) {
  int row = blockIdx.x;          // b*64+l, 0..1023
  int t = threadIdx.x;
  const float* p = probas + (size_t)row * 16384;
  __shared__ unsigned long long lists[256][16];  // fallback scratch; cand alias
  __shared__ float swsum[4];
  __shared__ int lcnt;
  unsigned long long* cand = &lists[0][0];  // first 512 slots

  cand[t] = 0ull;
  cand[t + 256] = 0ull;
  if (t == 0) lcnt = 0;
  __syncthreads();

  const uint32_t TB = 0x3F7E0000u;  // ~0.984375; E[cnt] = 16384/128 = 128
  float sum = 0.f;
  const float4* p4 = (const float4*)p;
#pragma unroll 4
  for (int j = 0; j < 16; ++j) {
    float4 x = p4[t + j * 256];
    int v0 = (t + j * 256) * 4;
    uint32_t u0 = __float_as_uint(x.x), u1 = __float_as_uint(x.y);
    uint32_t u2 = __float_as_uint(x.z), u3 = __float_as_uint(x.w);
    sum += x.x; sum += x.y; sum += x.z; sum += x.w;
    uint32_t um = max(max(u0, u1), max(u2, u3));
    if (um >= TB) {  // rare: ~6% of lane-iterations
      if (u0 >= TB) { int s = atomicAdd(&lcnt, 1); if (s < 512)
          cand[s] = ((unsigned long long)u0 << 32) | (unsigned)(~(v0 + 0)); }
      if (u1 >= TB) { int s = atomicAdd(&lcnt, 1); if (s < 512)
          cand[s] = ((unsigned long long)u1 << 32) | (unsigned)(~(v0 + 1)); }
      if (u2 >= TB) { int s = atomicAdd(&lcnt, 1); if (s < 512)
          cand[s] = ((unsigned long long)u2 << 32) | (unsigned)(~(v0 + 2)); }
      if (u3 >= TB) { int s = atomicAdd(&lcnt, 1); if (s < 512)
          cand[s] = ((unsigned long long)u3 << 32) | (unsigned)(~(v0 + 3)); }
    }
  }
#pragma unroll
  for (int off = 32; off >= 1; off >>= 1) sum += __shfl_down(sum, off);
  if ((t & 63) == 0) swsum[t >> 6] = sum;
  __syncthreads();
  if (t == 0) S[row] = ((swsum[0] + swsum[1]) + swsum[2]) + swsum[3];

  int n = lcnt;
  if (n >= 16 && n <= 512) {
    // -------- selection: one wave, 16 rounds of argmax-and-remove --------
    if (t < 64) {
      unsigned long long c[8];
#pragma unroll
      for (int k = 0; k < 8; ++k) c[k] = cand[t + 64 * k];  // pad slots are 0
      unsigned long long win = 0ull;
#pragma unroll
      for (int r = 0; r < 16; ++r) {
        unsigned long long m = c[0];
#pragma unroll
        for (int k = 1; k < 8; ++k) m = u64max(m, c[k]);
#pragma unroll
        for (int off = 32; off >= 1; off >>= 1) {
          unsigned long long o = __shfl_xor(m, off);
          m = u64max(m, o);
        }
        if (t == r) win = m;   // r is a literal (unrolled)
#pragma unroll
        for (int k = 0; k < 8; ++k) if (c[k] == m) c[k] = 0ull;  // unique keys
      }
      if (t < 16) {
        int idx = (int)(~(unsigned)(win & 0xFFFFFFFFull));
        float val = __uint_as_float((unsigned)(win >> 32));
        topk_idx[row * 16 + t] = idx;
        // masked rows: topk_vals := 1.0 -> logit 0
        logits[row * 16 + t] = (mask[row] == 0) ? 0.0f : logf_ref(val);
      }
    }
    return;
  }

  // -------------------- fallback: original exact path ----------------------
  {
    unsigned long long loc[16];
#pragma unroll
    for (int q = 0; q < 16; ++q) loc[q] = 0ull;
    for (int j = 0; j < 64; ++j) {
      int v = t + j * 256;
      float x = p[v];
      unsigned long long key =
          ((unsigned long long)__float_as_uint(x) << 32) | (unsigned)(~v);
      if (key > loc[15]) {
        loc[15] = key;
#pragma unroll
        for (int q = 15; q > 0; --q) {
          if (loc[q] > loc[q - 1]) {
            unsigned long long tmp = loc[q]; loc[q] = loc[q - 1]; loc[q - 1] = tmp;
          }
        }
      }
    }
    __syncthreads();  // cand region about to be overwritten
#pragma unroll
    for (int q = 0; q < 16; ++q) lists[t][q] = loc[q];
    __syncthreads();
    for (int nl = 128; nl >= 1; nl >>= 1) {
      if (t < nl) {
        unsigned long long M[16];
        int ia = 0, ib = 0;
#pragma unroll
        for (int q = 0; q < 16; ++q) {
          unsigned long long av = lists[t][ia];
          unsigned long long bv = lists[t + nl][ib];
          if (av >= bv) { M[q] = av; ia++; } else { M[q] = bv; ib++; }
        }
#pragma unroll
        for (int q = 0; q < 16; ++q) lists[t][q] = M[q];
      }
      __syncthreads();
    }
    if (t < 16) {
      unsigned long long key = lists[0][t];
      int idx = (int)(~(unsigned)(key & 0xFFFFFFFFull));
      float val = __uint_as_float((unsigned)(key >> 32));
      topk_idx[row * 16 + t] = idx;
      logits[row * 16 + t] = (mask[row] == 0) ? 0.0f : logf_ref(val);
    }
  }
}

// ------------------------ gumbel categorical sampling ----------------------
__global__ __launch_bounds__(256) void k_sample(Keys16 keys,
                                                const int* __restrict__ mask,
                                                const int* __restrict__ topk_idx,
                                                const float* __restrict__ logits,
                                                int* __restrict__ samples,
                                                int* __restrict__ choice) {
  int tid = blockIdx.x * 256 + threadIdx.x;  // 0..8191 = i*1024 + b*64 + l
  int i = tid >> 10;
  int rbl = tid & 1023;
  int b = rbl >> 6;
  int l = rbl & 63;
  uint32_t k0 = keys.k[2 * i], k1 = keys.k[2 * i + 1];
  int sl = 0;
  for (int m = 0; m < 64; ++m) sl += mask[b * 64 + m];
  float bestv = 0.f; int bestk = 0;
#pragma unroll
  for (int k = 0; k < 16; ++k) {
    uint32_t j = (uint32_t)((b * 64 + l) * 16 + k);  // flat idx in (16,64,16)
    uint32_t y0, y1;
    tf2x32(k0, k1, 0u, j, &y0, &y1);
    uint32_t bits = y0 ^ y1;  // 32-bit path: convert_element_type(bits1 ^ bits2)
    float f = __uint_as_float((bits >> 9) | 0x3f800000u) - 1.0f;
    float u = fmaxf(TINYF, f * 1.0f + TINYF);     // uniform(tiny, 1)
    float t1 = logf_ref(u);
    float g = -logf_ref(-t1);                      // gumbel
    float sv = g + logits[rbl * 16 + k];
    if (k == 0 || sv > bestv) { bestv = sv; bestk = k; }  // first-max
  }
  int ce = (l == sl - 1) ? 0 : bestk;  // one_hot: last valid pos -> MAP (=top1)
  choice[tid] = ce;
  samples[tid] = topk_idx[rbl * 16 + ce];
}

// -- Eall[row,slot,:] = relu(mk*(emb[bv[topk[row,k(slot)]]]@W1a)+h@W1b+b1) --
// R6: only k in union(choice_i(row)) are computed (<=8 slots). slot(k) =
// popc(mb & ((1<<k)-1)), mb = OR_i (1<<choice_i). Pad slots duplicate the
// lowest set bit (never read by gram). fma chains per slot == R4 (bit-exact).
__global__ __launch_bounds__(256) void k_ce(const int* __restrict__ topk_idx,
                                            const int* __restrict__ batch_vocab,
                                            const float* __restrict__ emb,
                                            const float* __restrict__ W1,
                                            const float* __restrict__ h_d,
                                            const float* __restrict__ b1,
                                            const int* __restrict__ mask,
                                            const int* __restrict__ choice,
                                            float* __restrict__ Eall) {
  int row = blockIdx.x;  // b*64+l
  int t = threadIdx.x;   // d
  __shared__ int smb;
  __shared__ int rid[8];
  __shared__ float e[8][256];
  __shared__ float hl[256];
  if (t == 0) smb = 0;
  float mkf = (float)mask[row];
  hl[t] = h_d[(size_t)row * 256 + t] * mkf;   // == old k_h1 staging
  __syncthreads();
  if (t < 8) atomicOr(&smb, 1 << choice[t * 1024 + row]);
  __syncthreads();
  int mb = smb;
  if (t < 8) {
    int cnt = __popc(mb);
    int ss = (t < cnt) ? t : 0;  // pad: lowest set bit (slot never read)
    int kk = 0;
    for (int bit = 0; bit < 16; ++bit) {
      if ((mb >> bit) & 1) {
        if (ss == 0) { kk = bit; break; }
        ss--;
      }
    }
    rid[t] = batch_vocab[topk_idx[row * 16 + kk]];
  }
  __syncthreads();
#pragma unroll
  for (int k = 0; k < 8; ++k) e[k][t] = emb[(size_t)rid[k] * 256 + t];
  __syncthreads();
  // H1 part (identical chain to old k_h1)
  float acch = 0.f;
  for (int j0 = 0; j0 < 256; j0 += 4) {
    float4 hv = *(const float4*)&hl[j0];
    float w0 = W1[(256 + j0 + 0) * 256 + t];
    float w1 = W1[(256 + j0 + 1) * 256 + t];
    float w2 = W1[(256 + j0 + 2) * 256 + t];
    float w3 = W1[(256 + j0 + 3) * 256 + t];
    acch = fmaf(hv.x, w0, acch);
    acch = fmaf(hv.y, w1, acch);
    acch = fmaf(hv.z, w2, acch);
    acch = fmaf(hv.w, w3, acch);
  }
  // C part (identical chain to old k_c, per computed slot)
  float acc[8];
#pragma unroll
  for (int k = 0; k < 8; ++k) acc[k] = 0.f;
  for (int j0 = 0; j0 < 256; j0 += 4) {
    float w0 = W1[(j0 + 0) * 256 + t];
    float w1 = W1[(j0 + 1) * 256 + t];
    float w2 = W1[(j0 + 2) * 256 + t];
    float w3 = W1[(j0 + 3) * 256 + t];
#pragma unroll
    for (int k = 0; k < 8; ++k) {
      float4 ev = *(const float4*)&e[k][j0];  // wave-uniform broadcast
      acc[k] = fmaf(ev.x, w0, acc[k]);
      acc[k] = fmaf(ev.y, w1, acc[k]);
      acc[k] = fmaf(ev.z, w2, acc[k]);
      acc[k] = fmaf(ev.w, w3, acc[k]);
    }
  }
  float b1v = b1[t];
#pragma unroll
  for (int k = 0; k < 8; ++k) {
    // old k_gram: val = mk*cv + H1 + b1 (mk in {0,1} -> contraction-invariant)
    float val = fmaf(mkf, acc[k], acch) + b1v;
    Eall[((size_t)row * 8 + k) * 256 + t] = fmaxf(val, 0.0f);
  }
}

// --------- per (iter, batch): gather E rows, K=E E^T, det via LU -----------
// Gram: transposed LDS tile, ds_read_b128; E indexed by slot (see k_ce).
// LU: wave 0, matrix in TRUE registers: runtime p-loop + fixed-bound
// unrolled c-loop (compile-time km[] indices); curcol register carries the
// search column. Values/order identical to serial LU.
__global__ __launch_bounds__(256, 1) void k_gram(const float* __restrict__ Eall,
                                                 const int* __restrict__ mask,
                                                 const int* __restrict__ choice,
                                                 float* __restrict__ scores) {
  int blk = blockIdx.x;  // i*16 + b
  int i = blk >> 4, b = blk & 15;
  int t = threadIdx.x;
  __shared__ __align__(16) float Ett[64][68];   // per-dt chunk of E^T
  __shared__ __align__(16) float KmF[64 * 68];  // XOR-swizzled (KMX)
  __shared__ int ch[64];
  int mskv = 0;
  if (t < 64) {
    int rowi = b * 64 + t;
    int ml = 0;
#pragma unroll
    for (int ii = 0; ii < 8; ++ii) ml |= 1 << choice[ii * 1024 + rowi];
    int cc = choice[i * 1024 + rowi];
    ch[t] = __popc(ml & ((1 << cc) - 1));  // slot of this iter's choice
    mskv = mask[rowi];  // prefetch for LU
  }
  __syncthreads();
  int l = t & 63, wd = t >> 6;  // wd: which 16-d slab of the 64-d chunk
  const float* eptr =
      Eall + ((size_t)((b * 64 + l) * 8 + ch[l])) * 256 + wd * 16;
  float acc[16];
#pragma unroll
  for (int q = 0; q < 16; ++q) acc[q] = 0.f;
  int tx = t & 15, ty = t >> 4;
  for (int dt = 0; dt < 4; ++dt) {
    const float* src = eptr + dt * 64;
    float4 v0 = *(const float4*)(src + 0);
    float4 v1 = *(const float4*)(src + 4);
    float4 v2 = *(const float4*)(src + 8);
    float4 v3 = *(const float4*)(src + 12);
    int d0 = wd * 16;
    Ett[d0 +  0][l] = v0.x; Ett[d0 +  1][l] = v0.y;
    Ett[d0 +  2][l] = v0.z; Ett[d0 +  3][l] = v0.w;
    Ett[d0 +  4][l] = v1.x; Ett[d0 +  5][l] = v1.y;
    Ett[d0 +  6][l] = v1.z; Ett[d0 +  7][l] = v1.w;
    Ett[d0 +  8][l] = v2.x; Ett[d0 +  9][l] = v2.y;
    Ett[d0 + 10][l] = v2.z; Ett[d0 + 11][l] = v2.w;
    Ett[d0 + 12][l] = v3.x; Ett[d0 + 13][l] = v3.y;
    Ett[d0 + 14][l] = v3.z; Ett[d0 + 15][l] = v3.w;
    __syncthreads();
#pragma unroll 4
    for (int dd = 0; dd < 64; ++dd) {   // d ascending: same acc order as before
      float4 av4 = *(const float4*)&Ett[dd][tx * 4];
      float4 bv4 = *(const float4*)&Ett[dd][ty * 4];
      float avv[4] = {av4.x, av4.y, av4.z, av4.w};
      float bvv[4] = {bv4.x, bv4.y, bv4.z, bv4.w};
#pragma unroll
      for (int a2 = 0; a2 < 4; ++a2)
#pragma unroll
        for (int c2 = 0; c2 < 4; ++c2)
          acc[a2 * 4 + c2] = fmaf(avv[a2], bvv[c2], acc[a2 * 4 + c2]);
    }
    __syncthreads();
  }
#pragma unroll
  for (int a2 = 0; a2 < 4; ++a2)
#pragma unroll
    for (int c2 = 0; c2 < 4; ++c2)
      KmF[KMX(tx * 4 + a2, ty * 4 + c2)] = acc[a2 * 4 + c2];
  __syncthreads();
  if (t >= 64) return;  // waves 1-3 done; wave 0 runs the LU

  unsigned long long bal = __ballot(mskv != 0);
  int L = __popcll(bal);  // prefix mask => leading LxL block

  // lane t owns original row t in registers (all indices compile-time)
  float km[64];
#pragma unroll
  for (int c0 = 0; c0 < 64; c0 += 4) {
    float4 v = *(const float4*)&KmF[KMX(t, c0)];
    km[c0 + 0] = v.x; km[c0 + 1] = v.y; km[c0 + 2] = v.z; km[c0 + 3] = v.w;
  }

  float sdet = 1.f, ssign = 1.f;   // uniform across lanes
  int pos = t;                      // current position of original row t
  float curcol = km[0];             // this row's entry in search column 0

#pragma unroll 1
  for (int p = 0; p < L; ++p) {     // runtime loop: compact code, no spill
    // candidates: unretired rows (current positions p..L-1)
    bool cnd = (pos >= p) && (pos < L);
    unsigned lo = (((unsigned)(63 - pos)) << 6) | (unsigned)t;
    unsigned long long key =
        cnd ? ((((unsigned long long)__float_as_uint(fabsf(curcol))) << 32) | lo)
            : 0ull;
#pragma unroll
    for (int off = 32; off >= 1; off >>= 1) {
      unsigned long long o = __shfl_xor(key, off);
      if (o > key) key = o;
    }
    int lane_rb = (int)(key & 63u);            // original row idx of winner
    int pb = 63 - (int)((key >> 6) & 63u);     // winner's current position
    int srb = __builtin_amdgcn_readfirstlane(lane_rb);  // -> SGPR
    float kpp = lane_bcast_f32(curcol, srb);   // signed pivot value
    sdet *= kpp;                               // ascending product order
    if (pb != p) ssign = -ssign;               // ipiv parity == swap parity
    // virtual swap: displaced row -> pb, winner -> p (retired)
    int np = pos;
    if (pos == p) np = pb;
    if (t == lane_rb) np = p;
    pos = np;
    // eliminate current rows p+1..L-1; inactive lanes get f=0 (no-op +-0)
    bool active = (pos > p) && (pos < L);
    float f = (active && kpp != 0.f) ? (curcol / kpp) : 0.f;  // IEEE f32 div
    float nf = -f;
    float ncc = curcol;
    int pp1 = p + 1;
#pragma unroll
    for (int chk = 0; chk < 8; ++chk) {
      if (chk * 8 + 7 >= pp1) {     // uniform branch: skip all-dead chunks
#pragma unroll
        for (int cc = 0; cc < 8; ++cc) {
          const int c = chk * 8 + cc;              // compile-time index
          float pr = lane_bcast_f32(km[c], srb);   // pivot row entry (SGPR)
          float nv = fmaf(nf, pr, km[c]);
          km[c] = nv;
          ncc = (c == pp1) ? nv : ncc;  // capture next search column
        }
      }
    }
    curcol = ncc;
  }
  if (t == 0) scores[i * 16 + b] = sdet * ssign;
}

// ------------- diverse_proba (+ inlined improve/early-stop scan) -----------
__global__ __launch_bounds__(256) void k_out(const float* __restrict__ probas,
                                             const int* __restrict__ mask,
                                             const int* __restrict__ samples,
                                             const int* __restrict__ topk_idx,
                                             const float* __restrict__ scores,
                                             const float* __restrict__ S,
                                             float* __restrict__ out,
                                             float* __restrict__ out_ms) {
  int row = blockIdx.x;  // b*64+l
  int b = row >> 6;
  int t = threadIdx.x;
  __shared__ float ssc[128];
  if (t < 128) ssc[t] = scores[t];
  __syncthreads();
  // winner scan (== old k_select), unrolled -> compile-time reg indices
  float ms[16]; int w[16];
#pragma unroll
  for (int q = 0; q < 16; ++q) { ms[q] = -INFINITY; w[q] = -1; }
  int count = 0; bool stopped = false;
#pragma unroll
  for (int i = 0; i < 8; ++i) {
    bool any = false; bool imp[16];
#pragma unroll
    for (int q = 0; q < 16; ++q) {
      imp[q] = ssc[i * 16 + q] > ms[q];
      any = any || imp[q];
    }
    count = any ? 0 : (count + 1);
#pragma unroll
    for (int q = 0; q < 16; ++q) {
      if (imp[q] && !stopped) { ms[q] = ssc[i * 16 + q]; w[q] = i; }
    }
    stopped = stopped || ((!any) && (count >= 2));
  }
  if (row == 0 && t == 0) {
#pragma unroll
    for (int q = 0; q < 16; ++q) out_ms[q] = ms[q];  // max_score output
  }
  int wi = -1;
#pragma unroll
  for (int q = 0; q < 16; ++q) if (b == q) wi = w[q];  // const-index select

  int best = (wi >= 0) ? samples[wi * 1024 + row] : topk_idx[row * 16];
  const float* p = probas + (size_t)row * 16384;
  float* o = out + (size_t)row * 16384;
  float nm;
  if (mask[row] == 0) {
    nm = 1e-10f;  // matches ref bit-for-bit (the only rows that matter)
  } else {
    nm = 0.2f * S[row] + 0.6f * p[best];  // values ~6e-4, far below threshold
  }
  const float4* p4 = (const float4*)p;
  float4* o4 = (float4*)o;
  for (int f = t; f < 4096; f += 256) {
    float4 x = p4[f];
    int v0 = f << 2;
    float4 r;
    // per element: x * am / nm — identical ops/order to scalar version
    r.x = x.x * ((v0 + 0 == best) ? 0.8f : 0.2f) / nm;
    r.y = x.y * ((v0 + 1 == best) ? 0.8f : 0.2f) / nm;
    r.z = x.z * ((v0 + 2 == best) ? 0.8f : 0.2f) / nm;
    r.w = x.w * ((v0 + 3 == best) ? 0.8f : 0.2f) / nm;
    o4[f] = r;
  }
}

// ---------------------------------------------------------------------------
extern "C" void kernel_launch(void* const* d_in, const int* in_sizes, int n_in,
                              void* d_out, int out_size, void* d_ws, size_t ws_size,
                              hipStream_t stream) {
  const float* probas = (const float*)d_in[0];
  const float* h_d    = (const float*)d_in[1];
  const int*   mask   = (const int*)d_in[2];
  const int*   bvoc   = (const int*)d_in[3];
  const float* emb    = (const float*)d_in[4];
  const float* W1     = (const float*)d_in[5];
  const float* b1     = (const float*)d_in[6];
  float* out = (float*)d_out;

  // small scratch in ws (~200 KB)
  char* w = (char*)d_ws;
  int*   topk_idx = (int*)w;   w += 16384 * sizeof(int);
  float* logits   = (float*)w; w += 16384 * sizeof(float);
  float* S        = (float*)w; w += 1024 * sizeof(float);
  int*   samples  = (int*)w;   w += 8192 * sizeof(int);
  int*   choice   = (int*)w;   w += 8192 * sizeof(int);
  float* scores   = (float*)w; w += 128 * sizeof(float);

  // large scratch lives inside d_out (rewritten by k_out at the end):
  // Eall: 16*64*8*256 = 2,097,152 floats (chosen slots only)
  float* Eall = out;

  // keys = jax.random.split(jax.random.key(42), 8) under PARTITIONABLE
  Keys16 keys;
  for (uint32_t i = 0; i < 8; ++i) {
    uint32_t a, bq;
    tf2x32(0u, 42u, 0u, i, &a, &bq);
    keys.k[2 * i] = a; keys.k[2 * i + 1] = bq;
  }

  k_topk<<<1024, 256, 0, stream>>>(probas, mask, topk_idx, logits, S);
  k_sample<<<32, 256, 0, stream>>>(keys, mask, topk_idx, logits, samples, choice);
  k_ce<<<1024, 256, 0, stream>>>(topk_idx, bvoc, emb, W1, h_d, b1, mask, choice,
                                 Eall);
  k_gram<<<128, 256, 0, stream>>>(Eall, mask, choice, scores);
  k_out<<<1024, 256, 0, stream>>>(probas, mask, samples, topk_idx, scores, S,
                                  out, out + 16777216);
}

// Round 7
// 281.723 us; speedup vs baseline: 1.7303x; 1.0573x over previous
//
#include <hip/hip_runtime.h>
#include <math.h>
#include <stdint.h>

// ---------------------------------------------------------------------------
// DPPSearch: NB=16, NL=64, V=16384, VOCAB=32000, D=256, TOPK=16, NITER=8
// Exact JAX threefry PARTITIONABLE stream (default since jax 0.4.36):
//   split(key,n)[i] = full pair of tf(key; 0, i)
//   random_bits(key,32,shape)[j] = y0 ^ y1 of tf(key; hi(j), lo(j))  <-- XOR fold
// f32 LU det winner scan. Masked rows of the output need bit-exact `best`.
//
// R1: k_gram single-wave LU + transposed-LDS gram.
// R2: k_topk threshold-gather top-16; k_out float4.
// R3: virtual pivoting (no row swaps, parity sign), reg-cached search col.
// R4/R5/R6 post-mortem: km[64] LOCAL ARRAY spilled to scratch TWICE
//     (VGPR_Count=52): SROA runs before unrolling, so loop-variant km[c]
//     keeps the alloca in scratch even with fully-unrollable loops.
// R6: k_ce chosen-slot compaction (<=8 of 16 slots; choice known pre-k_ce).
// R7: LU matrix in 16 NAMED float4 vars (r0..r15, macro-expanded) -- named
//     first-class vectors can't be runtime-indexed, so they MUST live in
//     VGPRs. Elimination: per-chunk uniform branch, 4 v_readlane + 4 v_fma
//     per chunk; curcol capture = 1 uniform branch + component select.
//     Zero LDS/scratch in the pivot loop. Values/order identical to the
//     serial LU (comparator, f, per-column fma order, sdet order, parity).
// ---------------------------------------------------------------------------

#define TINYF 1.17549435082228750797e-38f

// Km swizzled dword index: rows of 68 dwords; XOR c bits 2..4 by (r>>3)&7
#define KMX(r, c) (((r) * 68) + ((c) ^ ((((r) >> 3) & 7) << 2)))

struct Keys16 { uint32_t k[16]; };

__host__ __device__ inline void tf2x32(uint32_t k0, uint32_t k1,
                                       uint32_t x0, uint32_t x1,
                                       uint32_t* o0, uint32_t* o1) {
  uint32_t ks2 = k0 ^ k1 ^ 0x1BD11BDAu;
  uint32_t ks[3] = {k0, k1, ks2};
  uint32_t v0 = x0 + k0, v1 = x1 + k1;
  const int R0[4] = {13, 15, 26, 6};
  const int R1[4] = {17, 29, 16, 24};
#pragma unroll
  for (int g = 0; g < 5; ++g) {
    const int* RR = (g & 1) ? R1 : R0;
#pragma unroll
    for (int r = 0; r < 4; ++r) {
      v0 += v1;
      v1 = (v1 << RR[r]) | (v1 >> (32 - RR[r]));
      v1 ^= v0;
    }
    v0 += ks[(g + 1) % 3];
    v1 += ks[(g + 2) % 3] + (uint32_t)(g + 1);
  }
  *o0 = v0; *o1 = v1;
}

// f32 log emulated via f64 (<=1 ulp of numpy/XLA logf)
__device__ inline float logf_ref(float x) { return (float)log((double)x); }

__device__ inline unsigned long long u64max(unsigned long long a,
                                            unsigned long long b) {
  return (a > b) ? a : b;
}

// broadcast float from lane (uniform sgpr-resident) without LDS
__device__ inline float lane_bcast_f32(float v, int slane) {
  return __uint_as_float(
      (unsigned)__builtin_amdgcn_readlane(__float_as_int(v), slane));
}

// --------------------------- top-16 per row --------------------------------
__global__ __launch_bounds__(256) void k_topk(const float* __restrict__ probas,
                                              const int* __restrict__ mask,
                                              int* __restrict__ topk_idx,
                                              float* __restrict__ logits,
                                              float* __restrict__ S) {
  int row = blockIdx.x;          // b*64+l, 0..1023
  int t = threadIdx.x;
  const float* p = probas + (size_t)row * 16384;
  __shared__ unsigned long long lists[256][16];  // fallback scratch; cand alias
  __shared__ float swsum[4];
  __shared__ int lcnt;
  unsigned long long* cand = &lists[0][0];  // first 512 slots

  cand[t] = 0ull;
  cand[t + 256] = 0ull;
  if (t == 0) lcnt = 0;
  __syncthreads();

  const uint32_t TB = 0x3F7E0000u;  // ~0.984375; E[cnt] = 16384/128 = 128
  float sum = 0.f;
  const float4* p4 = (const float4*)p;
#pragma unroll 4
  for (int j = 0; j < 16; ++j) {
    float4 x = p4[t + j * 256];
    int v0 = (t + j * 256) * 4;
    uint32_t u0 = __float_as_uint(x.x), u1 = __float_as_uint(x.y);
    uint32_t u2 = __float_as_uint(x.z), u3 = __float_as_uint(x.w);
    sum += x.x; sum += x.y; sum += x.z; sum += x.w;
    uint32_t um = max(max(u0, u1), max(u2, u3));
    if (um >= TB) {  // rare: ~6% of lane-iterations
      if (u0 >= TB) { int s = atomicAdd(&lcnt, 1); if (s < 512)
          cand[s] = ((unsigned long long)u0 << 32) | (unsigned)(~(v0 + 0)); }
      if (u1 >= TB) { int s = atomicAdd(&lcnt, 1); if (s < 512)
          cand[s] = ((unsigned long long)u1 << 32) | (unsigned)(~(v0 + 1)); }
      if (u2 >= TB) { int s = atomicAdd(&lcnt, 1); if (s < 512)
          cand[s] = ((unsigned long long)u2 << 32) | (unsigned)(~(v0 + 2)); }
      if (u3 >= TB) { int s = atomicAdd(&lcnt, 1); if (s < 512)
          cand[s] = ((unsigned long long)u3 << 32) | (unsigned)(~(v0 + 3)); }
    }
  }
#pragma unroll
  for (int off = 32; off >= 1; off >>= 1) sum += __shfl_down(sum, off);
  if ((t & 63) == 0) swsum[t >> 6] = sum;
  __syncthreads();
  if (t == 0) S[row] = ((swsum[0] + swsum[1]) + swsum[2]) + swsum[3];

  int n = lcnt;
  if (n >= 16 && n <= 512) {
    // -------- selection: one wave, 16 rounds of argmax-and-remove --------
    if (t < 64) {
      unsigned long long c[8];
#pragma unroll
      for (int k = 0; k < 8; ++k) c[k] = cand[t + 64 * k];  // pad slots are 0
      unsigned long long win = 0ull;
#pragma unroll
      for (int r = 0; r < 16; ++r) {
        unsigned long long m = c[0];
#pragma unroll
        for (int k = 1; k < 8; ++k) m = u64max(m, c[k]);
#pragma unroll
        for (int off = 32; off >= 1; off >>= 1) {
          unsigned long long o = __shfl_xor(m, off);
          m = u64max(m, o);
        }
        if (t == r) win = m;   // r is a literal (unrolled)
#pragma unroll
        for (int k = 0; k < 8; ++k) if (c[k] == m) c[k] = 0ull;  // unique keys
      }
      if (t < 16) {
        int idx = (int)(~(unsigned)(win & 0xFFFFFFFFull));
        float val = __uint_as_float((unsigned)(win >> 32));
        topk_idx[row * 16 + t] = idx;
        // masked rows: topk_vals := 1.0 -> logit 0
        logits[row * 16 + t] = (mask[row] == 0) ? 0.0f : logf_ref(val);
      }
    }
    return;
  }

  // -------------------- fallback: original exact path ----------------------
  {
    unsigned long long loc[16];
#pragma unroll
    for (int q = 0; q < 16; ++q) loc[q] = 0ull;
    for (int j = 0; j < 64; ++j) {
      int v = t + j * 256;
      float x = p[v];
      unsigned long long key =
          ((unsigned long long)__float_as_uint(x) << 32) | (unsigned)(~v);
      if (key > loc[15]) {
        loc[15] = key;
#pragma unroll
        for (int q = 15; q > 0; --q) {
          if (loc[q] > loc[q - 1]) {
            unsigned long long tmp = loc[q]; loc[q] = loc[q - 1]; loc[q - 1] = tmp;
          }
        }
      }
    }
    __syncthreads();  // cand region about to be overwritten
#pragma unroll
    for (int q = 0; q < 16; ++q) lists[t][q] = loc[q];
    __syncthreads();
    for (int nl = 128; nl >= 1; nl >>= 1) {
      if (t < nl) {
        unsigned long long M[16];
        int ia = 0, ib = 0;
#pragma unroll
        for (int q = 0; q < 16; ++q) {
          unsigned long long av = lists[t][ia];
          unsigned long long bv = lists[t + nl][ib];
          if (av >= bv) { M[q] = av; ia++; } else { M[q] = bv; ib++; }
        }
#pragma unroll
        for (int q = 0; q < 16; ++q) lists[t][q] = M[q];
      }
      __syncthreads();
    }
    if (t < 16) {
      unsigned long long key = lists[0][t];
      int idx = (int)(~(unsigned)(key & 0xFFFFFFFFull));
      float val = __uint_as_float((unsigned)(key >> 32));
      topk_idx[row * 16 + t] = idx;
      logits[row * 16 + t] = (mask[row] == 0) ? 0.0f : logf_ref(val);
    }
  }
}

// ------------------------ gumbel categorical sampling ----------------------
__global__ __launch_bounds__(256) void k_sample(Keys16 keys,
                                                const int* __restrict__ mask,
                                                const int* __restrict__ topk_idx,
                                                const float* __restrict__ logits,
                                                int* __restrict__ samples,
                                                int* __restrict__ choice) {
  int tid = blockIdx.x * 256 + threadIdx.x;  // 0..8191 = i*1024 + b*64 + l
  int i = tid >> 10;
  int rbl = tid & 1023;
  int b = rbl >> 6;
  int l = rbl & 63;
  uint32_t k0 = keys.k[2 * i], k1 = keys.k[2 * i + 1];
  int sl = 0;
  for (int m = 0; m < 64; ++m) sl += mask[b * 64 + m];
  float bestv = 0.f; int bestk = 0;
#pragma unroll
  for (int k = 0; k < 16; ++k) {
    uint32_t j = (uint32_t)((b * 64 + l) * 16 + k);  // flat idx in (16,64,16)
    uint32_t y0, y1;
    tf2x32(k0, k1, 0u, j, &y0, &y1);
    uint32_t bits = y0 ^ y1;  // 32-bit path: convert_element_type(bits1 ^ bits2)
    float f = __uint_as_float((bits >> 9) | 0x3f800000u) - 1.0f;
    float u = fmaxf(TINYF, f * 1.0f + TINYF);     // uniform(tiny, 1)
    float t1 = logf_ref(u);
    float g = -logf_ref(-t1);                      // gumbel
    float sv = g + logits[rbl * 16 + k];
    if (k == 0 || sv > bestv) { bestv = sv; bestk = k; }  // first-max
  }
  int ce = (l == sl - 1) ? 0 : bestk;  // one_hot: last valid pos -> MAP (=top1)
  choice[tid] = ce;
  samples[tid] = topk_idx[rbl * 16 + ce];
}

// -- Eall[row,slot,:] = relu(mk*(emb[bv[topk[row,k(slot)]]]@W1a)+h@W1b+b1) --
// R6: only k in union(choice_i(row)) are computed (<=8 slots). slot(k) =
// popc(mb & ((1<<k)-1)), mb = OR_i (1<<choice_i). Pad slots duplicate the
// lowest set bit (never read by gram). fma chains per slot == R4 (bit-exact).
__global__ __launch_bounds__(256) void k_ce(const int* __restrict__ topk_idx,
                                            const int* __restrict__ batch_vocab,
                                            const float* __restrict__ emb,
                                            const float* __restrict__ W1,
                                            const float* __restrict__ h_d,
                                            const float* __restrict__ b1,
                                            const int* __restrict__ mask,
                                            const int* __restrict__ choice,
                                            float* __restrict__ Eall) {
  int row = blockIdx.x;  // b*64+l
  int t = threadIdx.x;   // d
  __shared__ int smb;
  __shared__ int rid[8];
  __shared__ float e[8][256];
  __shared__ float hl[256];
  if (t == 0) smb = 0;
  float mkf = (float)mask[row];
  hl[t] = h_d[(size_t)row * 256 + t] * mkf;   // == old k_h1 staging
  __syncthreads();
  if (t < 8) atomicOr(&smb, 1 << choice[t * 1024 + row]);
  __syncthreads();
  int mb = smb;
  if (t < 8) {
    int cnt = __popc(mb);
    int ss = (t < cnt) ? t : 0;  // pad: lowest set bit (slot never read)
    int kk = 0;
    for (int bit = 0; bit < 16; ++bit) {
      if ((mb >> bit) & 1) {
        if (ss == 0) { kk = bit; break; }
        ss--;
      }
    }
    rid[t] = batch_vocab[topk_idx[row * 16 + kk]];
  }
  __syncthreads();
#pragma unroll
  for (int k = 0; k < 8; ++k) e[k][t] = emb[(size_t)rid[k] * 256 + t];
  __syncthreads();
  // H1 part (identical chain to old k_h1)
  float acch = 0.f;
  for (int j0 = 0; j0 < 256; j0 += 4) {
    float4 hv = *(const float4*)&hl[j0];
    float w0 = W1[(256 + j0 + 0) * 256 + t];
    float w1 = W1[(256 + j0 + 1) * 256 + t];
    float w2 = W1[(256 + j0 + 2) * 256 + t];
    float w3 = W1[(256 + j0 + 3) * 256 + t];
    acch = fmaf(hv.x, w0, acch);
    acch = fmaf(hv.y, w1, acch);
    acch = fmaf(hv.z, w2, acch);
    acch = fmaf(hv.w, w3, acch);
  }
  // C part (identical chain to old k_c, per computed slot)
  float acc[8];
#pragma unroll
  for (int k = 0; k < 8; ++k) acc[k] = 0.f;
  for (int j0 = 0; j0 < 256; j0 += 4) {
    float w0 = W1[(j0 + 0) * 256 + t];
    float w1 = W1[(j0 + 1) * 256 + t];
    float w2 = W1[(j0 + 2) * 256 + t];
    float w3 = W1[(j0 + 3) * 256 + t];
#pragma unroll
    for (int k = 0; k < 8; ++k) {
      float4 ev = *(const float4*)&e[k][j0];  // wave-uniform broadcast
      acc[k] = fmaf(ev.x, w0, acc[k]);
      acc[k] = fmaf(ev.y, w1, acc[k]);
      acc[k] = fmaf(ev.z, w2, acc[k]);
      acc[k] = fmaf(ev.w, w3, acc[k]);
    }
  }
  float b1v = b1[t];
#pragma unroll
  for (int k = 0; k < 8; ++k) {
    // old k_gram: val = mk*cv + H1 + b1 (mk in {0,1} -> contraction-invariant)
    float val = fmaf(mkf, acc[k], acch) + b1v;
    Eall[((size_t)row * 8 + k) * 256 + t] = fmaxf(val, 0.0f);
  }
}

// --------- per (iter, batch): gather E rows, K=E E^T, det via LU -----------
// Gram: transposed LDS tile, ds_read_b128; E indexed by slot (see k_ce).
// LU: wave 0, matrix in 16 NAMED float4 VGPR variables (macro-expanded;
// cannot be runtime-indexed -> guaranteed register residency). Virtual
// pivoting; pivot row via v_readlane; zero LDS/scratch in the pivot loop.
__global__ __launch_bounds__(256, 1) void k_gram(const float* __restrict__ Eall,
                                                 const int* __restrict__ mask,
                                                 const int* __restrict__ choice,
                                                 float* __restrict__ scores) {
  int blk = blockIdx.x;  // i*16 + b
  int i = blk >> 4, b = blk & 15;
  int t = threadIdx.x;
  __shared__ __align__(16) float Ett[64][68];   // per-dt chunk of E^T
  __shared__ __align__(16) float KmF[64 * 68];  // XOR-swizzled (KMX)
  __shared__ int ch[64];
  int mskv = 0;
  if (t < 64) {
    int rowi = b * 64 + t;
    int ml = 0;
#pragma unroll
    for (int ii = 0; ii < 8; ++ii) ml |= 1 << choice[ii * 1024 + rowi];
    int cc = choice[i * 1024 + rowi];
    ch[t] = __popc(ml & ((1 << cc) - 1));  // slot of this iter's choice
    mskv = mask[rowi];  // prefetch for LU
  }
  __syncthreads();
  int l = t & 63, wd = t >> 6;  // wd: which 16-d slab of the 64-d chunk
  const float* eptr =
      Eall + ((size_t)((b * 64 + l) * 8 + ch[l])) * 256 + wd * 16;
  float acc[16];
#pragma unroll
  for (int q = 0; q < 16; ++q) acc[q] = 0.f;
  int tx = t & 15, ty = t >> 4;
  for (int dt = 0; dt < 4; ++dt) {
    const float* src = eptr + dt * 64;
    float4 v0 = *(const float4*)(src + 0);
    float4 v1 = *(const float4*)(src + 4);
    float4 v2 = *(const float4*)(src + 8);
    float4 v3 = *(const float4*)(src + 12);
    int d0 = wd * 16;
    Ett[d0 +  0][l] = v0.x; Ett[d0 +  1][l] = v0.y;
    Ett[d0 +  2][l] = v0.z; Ett[d0 +  3][l] = v0.w;
    Ett[d0 +  4][l] = v1.x; Ett[d0 +  5][l] = v1.y;
    Ett[d0 +  6][l] = v1.z; Ett[d0 +  7][l] = v1.w;
    Ett[d0 +  8][l] = v2.x; Ett[d0 +  9][l] = v2.y;
    Ett[d0 + 10][l] = v2.z; Ett[d0 + 11][l] = v2.w;
    Ett[d0 + 12][l] = v3.x; Ett[d0 + 13][l] = v3.y;
    Ett[d0 + 14][l] = v3.z; Ett[d0 + 15][l] = v3.w;
    __syncthreads();
#pragma unroll 4
    for (int dd = 0; dd < 64; ++dd) {   // d ascending: same acc order as before
      float4 av4 = *(const float4*)&Ett[dd][tx * 4];
      float4 bv4 = *(const float4*)&Ett[dd][ty * 4];
      float avv[4] = {av4.x, av4.y, av4.z, av4.w};
      float bvv[4] = {bv4.x, bv4.y, bv4.z, bv4.w};
#pragma unroll
      for (int a2 = 0; a2 < 4; ++a2)
#pragma unroll
        for (int c2 = 0; c2 < 4; ++c2)
          acc[a2 * 4 + c2] = fmaf(avv[a2], bvv[c2], acc[a2 * 4 + c2]);
    }
    __syncthreads();
  }
#pragma unroll
  for (int a2 = 0; a2 < 4; ++a2)
#pragma unroll
    for (int c2 = 0; c2 < 4; ++c2)
      KmF[KMX(tx * 4 + a2, ty * 4 + c2)] = acc[a2 * 4 + c2];
  __syncthreads();
  if (t >= 64) return;  // waves 1-3 done; wave 0 runs the LU

  unsigned long long bal = __ballot(mskv != 0);
  int L = __popcll(bal);  // prefix mask => leading LxL block

  // lane t owns original row t in 16 NAMED float4s (VGPR-guaranteed)
#define KM_DECL(i) float4 r##i = *(const float4*)&KmF[KMX(t, 4 * i)];
  KM_DECL(0)  KM_DECL(1)  KM_DECL(2)  KM_DECL(3)
  KM_DECL(4)  KM_DECL(5)  KM_DECL(6)  KM_DECL(7)
  KM_DECL(8)  KM_DECL(9)  KM_DECL(10) KM_DECL(11)
  KM_DECL(12) KM_DECL(13) KM_DECL(14) KM_DECL(15)
#undef KM_DECL

  float sdet = 1.f, ssign = 1.f;   // uniform across lanes
  int pos = t;                      // current position of original row t
  float curcol = r0.x;              // this row's entry in search column 0

#pragma unroll 1
  for (int p = 0; p < L; ++p) {     // runtime loop: compact code
    // candidates: unretired rows (current positions p..L-1)
    bool cnd = (pos >= p) && (pos < L);
    unsigned lo = (((unsigned)(63 - pos)) << 6) | (unsigned)t;
    unsigned long long key =
        cnd ? ((((unsigned long long)__float_as_uint(fabsf(curcol))) << 32) | lo)
            : 0ull;
#pragma unroll
    for (int off = 32; off >= 1; off >>= 1) {
      unsigned long long o = __shfl_xor(key, off);
      if (o > key) key = o;
    }
    int lane_rb = (int)(key & 63u);            // original row idx of winner
    int pb = 63 - (int)((key >> 6) & 63u);     // winner's current position
    int srb = __builtin_amdgcn_readfirstlane(lane_rb);  // -> SGPR
    float kpp = lane_bcast_f32(curcol, srb);   // signed pivot value
    sdet *= kpp;                               // ascending product order
    if (pb != p) ssign = -ssign;               // ipiv parity == swap parity
    // virtual swap: displaced row -> pb, winner -> p (retired)
    int np = pos;
    if (pos == p) np = pb;
    if (t == lane_rb) np = p;
    pos = np;
    // eliminate current rows p+1..L-1; inactive lanes get f=0 (no-op +-0)
    bool active = (pos > p) && (pos < L);
    float f = (active && kpp != 0.f) ? (curcol / kpp) : 0.f;  // IEEE f32 div
    float nf = -f;
    int pp1 = p + 1;
    // per 4-col chunk: uniform skip of all-dead chunks; pivot row via
    // readlane (SGPR); fma per column ascending == serial order. Dead cols
    // inside a live chunk get bounded garbage (|f|<=1), never read again.
#define KM_ELIM(i)                                                        \
    if (4 * i + 3 >= pp1) {                                               \
      float px = lane_bcast_f32(r##i.x, srb);                             \
      float py = lane_bcast_f32(r##i.y, srb);                             \
      float pz = lane_bcast_f32(r##i.z, srb);                             \
      float pw = lane_bcast_f32(r##i.w, srb);                             \
      r##i.x = fmaf(nf, px, r##i.x);                                      \
      r##i.y = fmaf(nf, py, r##i.y);                                      \
      r##i.z = fmaf(nf, pz, r##i.z);                                      \
      r##i.w = fmaf(nf, pw, r##i.w);                                      \
      if ((pp1 >> 2) == i) {  /* capture next search column (col pp1) */  \
        int sel = pp1 & 3;                                                \
        curcol = (sel == 0) ? r##i.x : (sel == 1) ? r##i.y                \
               : (sel == 2) ? r##i.z : r##i.w;                            \
      }                                                                   \
    }
    KM_ELIM(0)  KM_ELIM(1)  KM_ELIM(2)  KM_ELIM(3)
    KM_ELIM(4)  KM_ELIM(5)  KM_ELIM(6)  KM_ELIM(7)
    KM_ELIM(8)  KM_ELIM(9)  KM_ELIM(10) KM_ELIM(11)
    KM_ELIM(12) KM_ELIM(13) KM_ELIM(14) KM_ELIM(15)
#undef KM_ELIM
  }
  if (t == 0) scores[i * 16 + b] = sdet * ssign;
}

// ------------- diverse_proba (+ inlined improve/early-stop scan) -----------
__global__ __launch_bounds__(256) void k_out(const float* __restrict__ probas,
                                             const int* __restrict__ mask,
                                             const int* __restrict__ samples,
                                             const int* __restrict__ topk_idx,
                                             const float* __restrict__ scores,
                                             const float* __restrict__ S,
                                             float* __restrict__ out,
                                             float* __restrict__ out_ms) {
  int row = blockIdx.x;  // b*64+l
  int b = row >> 6;
  int t = threadIdx.x;
  __shared__ float ssc[128];
  if (t < 128) ssc[t] = scores[t];
  __syncthreads();
  // winner scan (== old k_select), unrolled -> compile-time reg indices
  float ms[16]; int w[16];
#pragma unroll
  for (int q = 0; q < 16; ++q) { ms[q] = -INFINITY; w[q] = -1; }
  int count = 0; bool stopped = false;
#pragma unroll
  for (int i = 0; i < 8; ++i) {
    bool any = false; bool imp[16];
#pragma unroll
    for (int q = 0; q < 16; ++q) {
      imp[q] = ssc[i * 16 + q] > ms[q];
      any = any || imp[q];
    }
    count = any ? 0 : (count + 1);
#pragma unroll
    for (int q = 0; q < 16; ++q) {
      if (imp[q] && !stopped) { ms[q] = ssc[i * 16 + q]; w[q] = i; }
    }
    stopped = stopped || ((!any) && (count >= 2));
  }
  if (row == 0 && t == 0) {
#pragma unroll
    for (int q = 0; q < 16; ++q) out_ms[q] = ms[q];  // max_score output
  }
  int wi = -1;
#pragma unroll
  for (int q = 0; q < 16; ++q) if (b == q) wi = w[q];  // const-index select

  int best = (wi >= 0) ? samples[wi * 1024 + row] : topk_idx[row * 16];
  const float* p = probas + (size_t)row * 16384;
  float* o = out + (size_t)row * 16384;
  float nm;
  if (mask[row] == 0) {
    nm = 1e-10f;  // matches ref bit-for-bit (the only rows that matter)
  } else {
    nm = 0.2f * S[row] + 0.6f * p[best];  // values ~6e-4, far below threshold
  }
  const float4* p4 = (const float4*)p;
  float4* o4 = (float4*)o;
  for (int f = t; f < 4096; f += 256) {
    float4 x = p4[f];
    int v0 = f << 2;
    float4 r;
    // per element: x * am / nm — identical ops/order to scalar version
    r.x = x.x * ((v0 + 0 == best) ? 0.8f : 0.2f) / nm;
    r.y = x.y * ((v0 + 1 == best) ? 0.8f : 0.2f) / nm;
    r.z = x.z * ((v0 + 2 == best) ? 0.8f : 0.2f) / nm;
    r.w = x.w * ((v0 + 3 == best) ? 0.8f : 0.2f) / nm;
    o4[f] = r;
  }
}

// ---------------------------------------------------------------------------
extern "C" void kernel_launch(void* const* d_in, const int* in_sizes, int n_in,
                              void* d_out, int out_size, void* d_ws, size_t ws_size,
                              hipStream_t stream) {
  const float* probas = (const float*)d_in[0];
  const float* h_d    = (const float*)d_in[1];
  const int*   mask   = (const int*)d_in[2];
  const int*   bvoc   = (const int*)d_in[3];
  const float* emb    = (const float*)d_in[4];
  const float* W1     = (const float*)d_in[5];
  const float* b1     = (const float*)d_in[6];
  float* out = (float*)d_out;

  // small scratch in ws (~200 KB)
  char* w = (char*)d_ws;
  int*   topk_idx = (int*)w;   w += 16384 * sizeof(int);
  float* logits   = (float*)w; w += 16384 * sizeof(float);
  float* S        = (float*)w; w += 1024 * sizeof(float);
  int*   samples  = (int*)w;   w += 8192 * sizeof(int);
  int*   choice   = (int*)w;   w += 8192 * sizeof(int);
  float* scores   = (float*)w; w += 128 * sizeof(float);

  // large scratch lives inside d_out (rewritten by k_out at the end):
  // Eall: 16*64*8*256 = 2,097,152 floats (chosen slots only)
  float* Eall = out;

  // keys = jax.random.split(jax.random.key(42), 8) under PARTITIONABLE
  Keys16 keys;
  for (uint32_t i = 0; i < 8; ++i) {
    uint32_t a, bq;
    tf2x32(0u, 42u, 0u, i, &a, &bq);
    keys.k[2 * i] = a; keys.k[2 * i + 1] = bq;
  }

  k_topk<<<1024, 256, 0, stream>>>(probas, mask, topk_idx, logits, S);
  k_sample<<<32, 256, 0, stream>>>(keys, mask, topk_idx, logits, samples, choice);
  k_ce<<<1024, 256, 0, stream>>>(topk_idx, bvoc, emb, W1, h_d, b1, mask, choice,
                                 Eall);
  k_gram<<<128, 256, 0, stream>>>(Eall, mask, choice, scores);
  k_out<<<1024, 256, 0, stream>>>(probas, mask, samples, topk_idx, scores, S,
                                  out, out + 16777216);
}

// Round 9
// 276.964 us; speedup vs baseline: 1.7600x; 1.0172x over previous
//
#include <hip/hip_runtime.h>
#include <math.h>
#include <stdint.h>

// ---------------------------------------------------------------------------
// DPPSearch: NB=16, NL=64, V=16384, VOCAB=32000, D=256, TOPK=16, NITER=8
// Exact JAX threefry PARTITIONABLE stream (default since jax 0.4.36):
//   split(key,n)[i] = full pair of tf(key; 0, i)
//   random_bits(key,32,shape)[j] = y0 ^ y1 of tf(key; hi(j), lo(j))  <-- XOR fold
// f32 LU det winner scan. Masked rows of the output need bit-exact `best`.
//
// R1: k_gram single-wave LU + transposed-LDS gram.
// R2: k_topk threshold-gather top-16; k_out float4.
// R3: virtual pivoting (no row swaps, parity sign), reg-cached search col.
// R4-R7 post-mortem: storage micro-opts (LDS->scratch->AGPR) only nibbled;
//     the real chain is the 6-level u64 shfl_xor pivot search (12 dependent
//     ds_bpermute ~ 700 cyc/pivot) serialized AFTER the elimination that
//     produces its input column.
// R8: (a) DPP wave64 max-reduce (row_shr 1/2/4/8 + row_bcast15/31, explicit
//     64-bit comparator on (hi,lo)) -- ~150 cyc pure VALU, zero LDS ops in
//     the pivot loop; max over unique keys -> bit-identical winner.
//     (b) two live columns (curcol=p, nextcol=p+1): eliminate nextcol first
//     (1 readlane+fma), launch the next reduce, THEN do the 16-chunk
//     elimination under it; chunk pass captures col p+2. Pivot-row fma is
//     exact identity (nf=-0.0), so the duplicated col-p+1 fma is bit-equal.
//     All FP values/order (kpp, f, fma per column, sdet, parity) unchanged.
// R9: R8 bench was an infra failure (container died twice, no counters);
//     diff vs working R7 is register-only VALU ops -> resubmit unchanged.
// ---------------------------------------------------------------------------

#define TINYF 1.17549435082228750797e-38f

// Km swizzled dword index: rows of 68 dwords; XOR c bits 2..4 by (r>>3)&7
#define KMX(r, c) (((r) * 68) + ((c) ^ ((((r) >> 3) & 7) << 2)))

struct Keys16 { uint32_t k[16]; };

__host__ __device__ inline void tf2x32(uint32_t k0, uint32_t k1,
                                       uint32_t x0, uint32_t x1,
                                       uint32_t* o0, uint32_t* o1) {
  uint32_t ks2 = k0 ^ k1 ^ 0x1BD11BDAu;
  uint32_t ks[3] = {k0, k1, ks2};
  uint32_t v0 = x0 + k0, v1 = x1 + k1;
  const int R0[4] = {13, 15, 26, 6};
  const int R1[4] = {17, 29, 16, 24};
#pragma unroll
  for (int g = 0; g < 5; ++g) {
    const int* RR = (g & 1) ? R1 : R0;
#pragma unroll
    for (int r = 0; r < 4; ++r) {
      v0 += v1;
      v1 = (v1 << RR[r]) | (v1 >> (32 - RR[r]));
      v1 ^= v0;
    }
    v0 += ks[(g + 1) % 3];
    v1 += ks[(g + 2) % 3] + (uint32_t)(g + 1);
  }
  *o0 = v0; *o1 = v1;
}

// f32 log emulated via f64 (<=1 ulp of numpy/XLA logf)
__device__ inline float logf_ref(float x) { return (float)log((double)x); }

__device__ inline unsigned long long u64max(unsigned long long a,
                                            unsigned long long b) {
  return (a > b) ? a : b;
}

// broadcast float from lane (uniform sgpr-resident) without LDS
__device__ inline float lane_bcast_f32(float v, int slane) {
  return __uint_as_float(
      (unsigned)__builtin_amdgcn_readlane(__float_as_int(v), slane));
}

// one DPP step of a wave64 (hi,lo) 64-bit max reduce. Invalid/masked lanes
// receive old=0 -> never taken (keys >= 0). Pure VALU, no LDS pipe.
template <int CTRL, int RMASK>
__device__ inline void dpp_max_step(unsigned& hi, unsigned& lo) {
  unsigned nh = (unsigned)__builtin_amdgcn_update_dpp(
      0, (int)hi, CTRL, RMASK, 0xF, false);
  unsigned nl = (unsigned)__builtin_amdgcn_update_dpp(
      0, (int)lo, CTRL, RMASK, 0xF, false);
  bool take = (nh > hi) || (nh == hi && nl > lo);
  hi = take ? nh : hi;
  lo = take ? nl : lo;
}

// after this, lane 63 holds the max (hi,lo) over all 64 lanes
__device__ inline void dpp_reduce_max64(unsigned& hi, unsigned& lo) {
  dpp_max_step<0x111, 0xF>(hi, lo);  // row_shr:1
  dpp_max_step<0x112, 0xF>(hi, lo);  // row_shr:2
  dpp_max_step<0x114, 0xF>(hi, lo);  // row_shr:4
  dpp_max_step<0x118, 0xF>(hi, lo);  // row_shr:8  -> lane 15+16k = row max
  dpp_max_step<0x142, 0xA>(hi, lo);  // row_bcast15 -> lane 31/63 = half max
  dpp_max_step<0x143, 0xC>(hi, lo);  // row_bcast31 -> lane 63 = global max
}

// --------------------------- top-16 per row --------------------------------
__global__ __launch_bounds__(256) void k_topk(const float* __restrict__ probas,
                                              const int* __restrict__ mask,
                                              int* __restrict__ topk_idx,
                                              float* __restrict__ logits,
                                              float* __restrict__ S) {
  int row = blockIdx.x;          // b*64+l, 0..1023
  int t = threadIdx.x;
  const float* p = probas + (size_t)row * 16384;
  __shared__ unsigned long long lists[256][16];  // fallback scratch; cand alias
  __shared__ float swsum[4];
  __shared__ int lcnt;
  unsigned long long* cand = &lists[0][0];  // first 512 slots

  cand[t] = 0ull;
  cand[t + 256] = 0ull;
  if (t == 0) lcnt = 0;
  __syncthreads();

  const uint32_t TB = 0x3F7E0000u;  // ~0.984375; E[cnt] = 16384/128 = 128
  float sum = 0.f;
  const float4* p4 = (const float4*)p;
#pragma unroll 4
  for (int j = 0; j < 16; ++j) {
    float4 x = p4[t + j * 256];
    int v0 = (t + j * 256) * 4;
    uint32_t u0 = __float_as_uint(x.x), u1 = __float_as_uint(x.y);
    uint32_t u2 = __float_as_uint(x.z), u3 = __float_as_uint(x.w);
    sum += x.x; sum += x.y; sum += x.z; sum += x.w;
    uint32_t um = max(max(u0, u1), max(u2, u3));
    if (um >= TB) {  // rare: ~6% of lane-iterations
      if (u0 >= TB) { int s = atomicAdd(&lcnt, 1); if (s < 512)
          cand[s] = ((unsigned long long)u0 << 32) | (unsigned)(~(v0 + 0)); }
      if (u1 >= TB) { int s = atomicAdd(&lcnt, 1); if (s < 512)
          cand[s] = ((unsigned long long)u1 << 32) | (unsigned)(~(v0 + 1)); }
      if (u2 >= TB) { int s = atomicAdd(&lcnt, 1); if (s < 512)
          cand[s] = ((unsigned long long)u2 << 32) | (unsigned)(~(v0 + 2)); }
      if (u3 >= TB) { int s = atomicAdd(&lcnt, 1); if (s < 512)
          cand[s] = ((unsigned long long)u3 << 32) | (unsigned)(~(v0 + 3)); }
    }
  }
#pragma unroll
  for (int off = 32; off >= 1; off >>= 1) sum += __shfl_down(sum, off);
  if ((t & 63) == 0) swsum[t >> 6] = sum;
  __syncthreads();
  if (t == 0) S[row] = ((swsum[0] + swsum[1]) + swsum[2]) + swsum[3];

  int n = lcnt;
  if (n >= 16 && n <= 512) {
    // -------- selection: one wave, 16 rounds of argmax-and-remove --------
    if (t < 64) {
      unsigned long long c[8];
#pragma unroll
      for (int k = 0; k < 8; ++k) c[k] = cand[t + 64 * k];  // pad slots are 0
      unsigned long long win = 0ull;
#pragma unroll
      for (int r = 0; r < 16; ++r) {
        unsigned long long m = c[0];
#pragma unroll
        for (int k = 1; k < 8; ++k) m = u64max(m, c[k]);
#pragma unroll
        for (int off = 32; off >= 1; off >>= 1) {
          unsigned long long o = __shfl_xor(m, off);
          m = u64max(m, o);
        }
        if (t == r) win = m;   // r is a literal (unrolled)
#pragma unroll
        for (int k = 0; k < 8; ++k) if (c[k] == m) c[k] = 0ull;  // unique keys
      }
      if (t < 16) {
        int idx = (int)(~(unsigned)(win & 0xFFFFFFFFull));
        float val = __uint_as_float((unsigned)(win >> 32));
        topk_idx[row * 16 + t] = idx;
        // masked rows: topk_vals := 1.0 -> logit 0
        logits[row * 16 + t] = (mask[row] == 0) ? 0.0f : logf_ref(val);
      }
    }
    return;
  }

  // -------------------- fallback: original exact path ----------------------
  {
    unsigned long long loc[16];
#pragma unroll
    for (int q = 0; q < 16; ++q) loc[q] = 0ull;
    for (int j = 0; j < 64; ++j) {
      int v = t + j * 256;
      float x = p[v];
      unsigned long long key =
          ((unsigned long long)__float_as_uint(x) << 32) | (unsigned)(~v);
      if (key > loc[15]) {
        loc[15] = key;
#pragma unroll
        for (int q = 15; q > 0; --q) {
          if (loc[q] > loc[q - 1]) {
            unsigned long long tmp = loc[q]; loc[q] = loc[q - 1]; loc[q - 1] = tmp;
          }
        }
      }
    }
    __syncthreads();  // cand region about to be overwritten
#pragma unroll
    for (int q = 0; q < 16; ++q) lists[t][q] = loc[q];
    __syncthreads();
    for (int nl = 128; nl >= 1; nl >>= 1) {
      if (t < nl) {
        unsigned long long M[16];
        int ia = 0, ib = 0;
#pragma unroll
        for (int q = 0; q < 16; ++q) {
          unsigned long long av = lists[t][ia];
          unsigned long long bv = lists[t + nl][ib];
          if (av >= bv) { M[q] = av; ia++; } else { M[q] = bv; ib++; }
        }
#pragma unroll
        for (int q = 0; q < 16; ++q) lists[t][q] = M[q];
      }
      __syncthreads();
    }
    if (t < 16) {
      unsigned long long key = lists[0][t];
      int idx = (int)(~(unsigned)(key & 0xFFFFFFFFull));
      float val = __uint_as_float((unsigned)(key >> 32));
      topk_idx[row * 16 + t] = idx;
      logits[row * 16 + t] = (mask[row] == 0) ? 0.0f : logf_ref(val);
    }
  }
}

// ------------------------ gumbel categorical sampling ----------------------
__global__ __launch_bounds__(256) void k_sample(Keys16 keys,
                                                const int* __restrict__ mask,
                                                const int* __restrict__ topk_idx,
                                                const float* __restrict__ logits,
                                                int* __restrict__ samples,
                                                int* __restrict__ choice) {
  int tid = blockIdx.x * 256 + threadIdx.x;  // 0..8191 = i*1024 + b*64 + l
  int i = tid >> 10;
  int rbl = tid & 1023;
  int b = rbl >> 6;
  int l = rbl & 63;
  uint32_t k0 = keys.k[2 * i], k1 = keys.k[2 * i + 1];
  int sl = 0;
  for (int m = 0; m < 64; ++m) sl += mask[b * 64 + m];
  float bestv = 0.f; int bestk = 0;
#pragma unroll
  for (int k = 0; k < 16; ++k) {
    uint32_t j = (uint32_t)((b * 64 + l) * 16 + k);  // flat idx in (16,64,16)
    uint32_t y0, y1;
    tf2x32(k0, k1, 0u, j, &y0, &y1);
    uint32_t bits = y0 ^ y1;  // 32-bit path: convert_element_type(bits1 ^ bits2)
    float f = __uint_as_float((bits >> 9) | 0x3f800000u) - 1.0f;
    float u = fmaxf(TINYF, f * 1.0f + TINYF);     // uniform(tiny, 1)
    float t1 = logf_ref(u);
    float g = -logf_ref(-t1);                      // gumbel
    float sv = g + logits[rbl * 16 + k];
    if (k == 0 || sv > bestv) { bestv = sv; bestk = k; }  // first-max
  }
  int ce = (l == sl - 1) ? 0 : bestk;  // one_hot: last valid pos -> MAP (=top1)
  choice[tid] = ce;
  samples[tid] = topk_idx[rbl * 16 + ce];
}

// -- Eall[row,slot,:] = relu(mk*(emb[bv[topk[row,k(slot)]]]@W1a)+h@W1b+b1) --
// R6: only k in union(choice_i(row)) are computed (<=8 slots). slot(k) =
// popc(mb & ((1<<k)-1)), mb = OR_i (1<<choice_i). Pad slots duplicate the
// lowest set bit (never read by gram). fma chains per slot == R4 (bit-exact).
__global__ __launch_bounds__(256) void k_ce(const int* __restrict__ topk_idx,
                                            const int* __restrict__ batch_vocab,
                                            const float* __restrict__ emb,
                                            const float* __restrict__ W1,
                                            const float* __restrict__ h_d,
                                            const float* __restrict__ b1,
                                            const int* __restrict__ mask,
                                            const int* __restrict__ choice,
                                            float* __restrict__ Eall) {
  int row = blockIdx.x;  // b*64+l
  int t = threadIdx.x;   // d
  __shared__ int smb;
  __shared__ int rid[8];
  __shared__ float e[8][256];
  __shared__ float hl[256];
  if (t == 0) smb = 0;
  float mkf = (float)mask[row];
  hl[t] = h_d[(size_t)row * 256 + t] * mkf;   // == old k_h1 staging
  __syncthreads();
  if (t < 8) atomicOr(&smb, 1 << choice[t * 1024 + row]);
  __syncthreads();
  int mb = smb;
  if (t < 8) {
    int cnt = __popc(mb);
    int ss = (t < cnt) ? t : 0;  // pad: lowest set bit (slot never read)
    int kk = 0;
    for (int bit = 0; bit < 16; ++bit) {
      if ((mb >> bit) & 1) {
        if (ss == 0) { kk = bit; break; }
        ss--;
      }
    }
    rid[t] = batch_vocab[topk_idx[row * 16 + kk]];
  }
  __syncthreads();
#pragma unroll
  for (int k = 0; k < 8; ++k) e[k][t] = emb[(size_t)rid[k] * 256 + t];
  __syncthreads();
  // H1 part (identical chain to old k_h1)
  float acch = 0.f;
  for (int j0 = 0; j0 < 256; j0 += 4) {
    float4 hv = *(const float4*)&hl[j0];
    float w0 = W1[(256 + j0 + 0) * 256 + t];
    float w1 = W1[(256 + j0 + 1) * 256 + t];
    float w2 = W1[(256 + j0 + 2) * 256 + t];
    float w3 = W1[(256 + j0 + 3) * 256 + t];
    acch = fmaf(hv.x, w0, acch);
    acch = fmaf(hv.y, w1, acch);
    acch = fmaf(hv.z, w2, acch);
    acch = fmaf(hv.w, w3, acch);
  }
  // C part (identical chain to old k_c, per computed slot)
  float acc[8];
#pragma unroll
  for (int k = 0; k < 8; ++k) acc[k] = 0.f;
  for (int j0 = 0; j0 < 256; j0 += 4) {
    float w0 = W1[(j0 + 0) * 256 + t];
    float w1 = W1[(j0 + 1) * 256 + t];
    float w2 = W1[(j0 + 2) * 256 + t];
    float w3 = W1[(j0 + 3) * 256 + t];
#pragma unroll
    for (int k = 0; k < 8; ++k) {
      float4 ev = *(const float4*)&e[k][j0];  // wave-uniform broadcast
      acc[k] = fmaf(ev.x, w0, acc[k]);
      acc[k] = fmaf(ev.y, w1, acc[k]);
      acc[k] = fmaf(ev.z, w2, acc[k]);
      acc[k] = fmaf(ev.w, w3, acc[k]);
    }
  }
  float b1v = b1[t];
#pragma unroll
  for (int k = 0; k < 8; ++k) {
    // old k_gram: val = mk*cv + H1 + b1 (mk in {0,1} -> contraction-invariant)
    float val = fmaf(mkf, acc[k], acch) + b1v;
    Eall[((size_t)row * 8 + k) * 256 + t] = fmaxf(val, 0.0f);
  }
}

// --------- per (iter, batch): gather E rows, K=E E^T, det via LU -----------
// Gram: transposed LDS tile, ds_read_b128; E indexed by slot (see k_ce).
// LU: wave 0; matrix in 16 named float4s. Virtual pivoting. Pivot search =
// DPP wave64 max-reduce (VALU only); search of pivot p+1 is launched right
// after the 1-column fast-path elimination and overlaps the 16-chunk
// elimination. Zero LDS ops in the pivot loop. Values/order identical to
// the serial LU (comparator incl. ties, f, fma per column, sdet, parity).
__global__ __launch_bounds__(256, 1) void k_gram(const float* __restrict__ Eall,
                                                 const int* __restrict__ mask,
                                                 const int* __restrict__ choice,
                                                 float* __restrict__ scores) {
  int blk = blockIdx.x;  // i*16 + b
  int i = blk >> 4, b = blk & 15;
  int t = threadIdx.x;
  __shared__ __align__(16) float Ett[64][68];   // per-dt chunk of E^T
  __shared__ __align__(16) float KmF[64 * 68];  // XOR-swizzled (KMX)
  __shared__ int ch[64];
  int mskv = 0;
  if (t < 64) {
    int rowi = b * 64 + t;
    int ml = 0;
#pragma unroll
    for (int ii = 0; ii < 8; ++ii) ml |= 1 << choice[ii * 1024 + rowi];
    int cc = choice[i * 1024 + rowi];
    ch[t] = __popc(ml & ((1 << cc) - 1));  // slot of this iter's choice
    mskv = mask[rowi];  // prefetch for LU
  }
  __syncthreads();
  int l = t & 63, wd = t >> 6;  // wd: which 16-d slab of the 64-d chunk
  const float* eptr =
      Eall + ((size_t)((b * 64 + l) * 8 + ch[l])) * 256 + wd * 16;
  float acc[16];
#pragma unroll
  for (int q = 0; q < 16; ++q) acc[q] = 0.f;
  int tx = t & 15, ty = t >> 4;
  for (int dt = 0; dt < 4; ++dt) {
    const float* src = eptr + dt * 64;
    float4 v0 = *(const float4*)(src + 0);
    float4 v1 = *(const float4*)(src + 4);
    float4 v2 = *(const float4*)(src + 8);
    float4 v3 = *(const float4*)(src + 12);
    int d0 = wd * 16;
    Ett[d0 +  0][l] = v0.x; Ett[d0 +  1][l] = v0.y;
    Ett[d0 +  2][l] = v0.z; Ett[d0 +  3][l] = v0.w;
    Ett[d0 +  4][l] = v1.x; Ett[d0 +  5][l] = v1.y;
    Ett[d0 +  6][l] = v1.z; Ett[d0 +  7][l] = v1.w;
    Ett[d0 +  8][l] = v2.x; Ett[d0 +  9][l] = v2.y;
    Ett[d0 + 10][l] = v2.z; Ett[d0 + 11][l] = v2.w;
    Ett[d0 + 12][l] = v3.x; Ett[d0 + 13][l] = v3.y;
    Ett[d0 + 14][l] = v3.z; Ett[d0 + 15][l] = v3.w;
    __syncthreads();
#pragma unroll 4
    for (int dd = 0; dd < 64; ++dd) {   // d ascending: same acc order as before
      float4 av4 = *(const float4*)&Ett[dd][tx * 4];
      float4 bv4 = *(const float4*)&Ett[dd][ty * 4];
      float avv[4] = {av4.x, av4.y, av4.z, av4.w};
      float bvv[4] = {bv4.x, bv4.y, bv4.z, bv4.w};
#pragma unroll
      for (int a2 = 0; a2 < 4; ++a2)
#pragma unroll
        for (int c2 = 0; c2 < 4; ++c2)
          acc[a2 * 4 + c2] = fmaf(avv[a2], bvv[c2], acc[a2 * 4 + c2]);
    }
    __syncthreads();
  }
#pragma unroll
  for (int a2 = 0; a2 < 4; ++a2)
#pragma unroll
    for (int c2 = 0; c2 < 4; ++c2)
      KmF[KMX(tx * 4 + a2, ty * 4 + c2)] = acc[a2 * 4 + c2];
  __syncthreads();
  if (t >= 64) return;  // waves 1-3 done; wave 0 runs the LU

  unsigned long long bal = __ballot(mskv != 0);
  int L = __popcll(bal);  // prefix mask => leading LxL block

  // lane t owns original row t in 16 named float4s
#define KM_DECL(i) float4 r##i = *(const float4*)&KmF[KMX(t, 4 * i)];
  KM_DECL(0)  KM_DECL(1)  KM_DECL(2)  KM_DECL(3)
  KM_DECL(4)  KM_DECL(5)  KM_DECL(6)  KM_DECL(7)
  KM_DECL(8)  KM_DECL(9)  KM_DECL(10) KM_DECL(11)
  KM_DECL(12) KM_DECL(13) KM_DECL(14) KM_DECL(15)
#undef KM_DECL

  float sdet = 1.f, ssign = 1.f;   // uniform across lanes
  int pos = t;                      // current position of original row t
  float curcol = r0.x;              // col p   (p = 0)
  float nextcol = r0.y;             // col p+1

  // preamble: launch pivot-0 search (key: |val| bits, then smallest current
  // position = reference first-max; low 6 bits = lane for winner decode)
  unsigned khi, klo;
  {
    bool cnd = (pos < L);
    khi = cnd ? __float_as_uint(fabsf(curcol)) : 0u;
    klo = cnd ? ((((unsigned)(63 - pos)) << 6) | (unsigned)t) : 0u;
    dpp_reduce_max64(khi, klo);
  }

#pragma unroll 1
  for (int p = 0; p < L; ++p) {
    // consume search result (winner sits in lane 63)
    unsigned lo63 = (unsigned)__builtin_amdgcn_readlane((int)klo, 63);
    int srb = (int)(lo63 & 63u);               // original row idx of winner
    int pb = 63 - (int)((lo63 >> 6) & 63u);    // winner's current position
    float kpp = lane_bcast_f32(curcol, srb);   // signed pivot value
    sdet *= kpp;                               // ascending product order
    if (pb != p) ssign = -ssign;               // ipiv parity == swap parity
    // virtual swap: displaced row -> pb, winner -> p (retired)
    int np = pos;
    if (pos == p) np = pb;
    if (t == srb) np = p;
    pos = np;
    // eliminate; inactive lanes get f = 0 (exact identity: x + -0*px == x)
    bool active = (pos > p) && (pos < L);
    float f = (active && kpp != 0.f) ? (curcol / kpp) : 0.f;  // IEEE f32 div
    float nf = -f;
    // fast path: col p+1 post-elim -> launch next search NOW (overlaps the
    // full elimination below). Pivot row unchanged -> prn == chunk's px.
    float prn = lane_bcast_f32(nextcol, srb);
    float nc1 = fmaf(nf, prn, nextcol);        // == chunk result, bit-exact
    int pp1 = p + 1, pp2 = p + 2;
    {
      bool cndn = (pos >= pp1) && (pos < L);
      khi = cndn ? __float_as_uint(fabsf(nc1)) : 0u;
      klo = cndn ? ((((unsigned)(63 - pos)) << 6) | (unsigned)t) : 0u;
      dpp_reduce_max64(khi, klo);              // VALU chain, runs under elim
    }
    float cap = nc1;  // default; overwritten when col p+2 exists
    // per 4-col chunk: uniform skip of all-dead chunks; pivot row via
    // readlane (SGPR); fma per column ascending == serial order. Dead cols
    // inside a live chunk get bounded garbage (|f|<=1), never read again.
#define KM_ELIM(i)                                                        \
    if (4 * i + 3 >= pp1) {                                               \
      float px = lane_bcast_f32(r##i.x, srb);                             \
      float py = lane_bcast_f32(r##i.y, srb);                             \
      float pz = lane_bcast_f32(r##i.z, srb);                             \
      float pw = lane_bcast_f32(r##i.w, srb);                             \
      r##i.x = fmaf(nf, px, r##i.x);                                      \
      r##i.y = fmaf(nf, py, r##i.y);                                      \
      r##i.z = fmaf(nf, pz, r##i.z);                                      \
      r##i.w = fmaf(nf, pw, r##i.w);                                      \
      if ((pp2 >> 2) == i) {  /* capture col p+2 (next nextcol) */        \
        int sel = pp2 & 3;                                                \
        cap = (sel == 0) ? r##i.x : (sel == 1) ? r##i.y                   \
            : (sel == 2) ? r##i.z : r##i.w;                               \
      }                                                                   \
    }
    KM_ELIM(0)  KM_ELIM(1)  KM_ELIM(2)  KM_ELIM(3)
    KM_ELIM(4)  KM_ELIM(5)  KM_ELIM(6)  KM_ELIM(7)
    KM_ELIM(8)  KM_ELIM(9)  KM_ELIM(10) KM_ELIM(11)
    KM_ELIM(12) KM_ELIM(13) KM_ELIM(14) KM_ELIM(15)
#undef KM_ELIM
    curcol = nc1;
    nextcol = cap;
  }
  if (t == 0) scores[i * 16 + b] = sdet * ssign;
}

// ------------- diverse_proba (+ inlined improve/early-stop scan) -----------
__global__ __launch_bounds__(256) void k_out(const float* __restrict__ probas,
                                             const int* __restrict__ mask,
                                             const int* __restrict__ samples,
                                             const int* __restrict__ topk_idx,
                                             const float* __restrict__ scores,
                                             const float* __restrict__ S,
                                             float* __restrict__ out,
                                             float* __restrict__ out_ms) {
  int row = blockIdx.x;  // b*64+l
  int b = row >> 6;
  int t = threadIdx.x;
  __shared__ float ssc[128];
  if (t < 128) ssc[t] = scores[t];
  __syncthreads();
  // winner scan (== old k_select), unrolled -> compile-time reg indices
  float ms[16]; int w[16];
#pragma unroll
  for (int q = 0; q < 16; ++q) { ms[q] = -INFINITY; w[q] = -1; }
  int count = 0; bool stopped = false;
#pragma unroll
  for (int i = 0; i < 8; ++i) {
    bool any = false; bool imp[16];
#pragma unroll
    for (int q = 0; q < 16; ++q) {
      imp[q] = ssc[i * 16 + q] > ms[q];
      any = any || imp[q];
    }
    count = any ? 0 : (count + 1);
#pragma unroll
    for (int q = 0; q < 16; ++q) {
      if (imp[q] && !stopped) { ms[q] = ssc[i * 16 + q]; w[q] = i; }
    }
    stopped = stopped || ((!any) && (count >= 2));
  }
  if (row == 0 && t == 0) {
#pragma unroll
    for (int q = 0; q < 16; ++q) out_ms[q] = ms[q];  // max_score output
  }
  int wi = -1;
#pragma unroll
  for (int q = 0; q < 16; ++q) if (b == q) wi = w[q];  // const-index select

  int best = (wi >= 0) ? samples[wi * 1024 + row] : topk_idx[row * 16];
  const float* p = probas + (size_t)row * 16384;
  float* o = out + (size_t)row * 16384;
  float nm;
  if (mask[row] == 0) {
    nm = 1e-10f;  // matches ref bit-for-bit (the only rows that matter)
  } else {
    nm = 0.2f * S[row] + 0.6f * p[best];  // values ~6e-4, far below threshold
  }
  const float4* p4 = (const float4*)p;
  float4* o4 = (float4*)o;
  for (int f = t; f < 4096; f += 256) {
    float4 x = p4[f];
    int v0 = f << 2;
    float4 r;
    // per element: x * am / nm — identical ops/order to scalar version
    r.x = x.x * ((v0 + 0 == best) ? 0.8f : 0.2f) / nm;
    r.y = x.y * ((v0 + 1 == best) ? 0.8f : 0.2f) / nm;
    r.z = x.z * ((v0 + 2 == best) ? 0.8f : 0.2f) / nm;
    r.w = x.w * ((v0 + 3 == best) ? 0.8f : 0.2f) / nm;
    o4[f] = r;
  }
}

// ---------------------------------------------------------------------------
extern "C" void kernel_launch(void* const* d_in, const int* in_sizes, int n_in,
                              void* d_out, int out_size, void* d_ws, size_t ws_size,
                              hipStream_t stream) {
  const float* probas = (const float*)d_in[0];
  const float* h_d    = (const float*)d_in[1];
  const int*   mask   = (const int*)d_in[2];
  const int*   bvoc   = (const int*)d_in[3];
  const float* emb    = (const float*)d_in[4];
  const float* W1     = (const float*)d_in[5];
  const float* b1     = (const float*)d_in[6];
  float* out = (float*)d_out;

  // small scratch in ws (~200 KB)
  char* w = (char*)d_ws;
  int*   topk_idx = (int*)w;   w += 16384 * sizeof(int);
  float* logits   = (float*)w; w += 16384 * sizeof(float);
  float* S        = (float*)w; w += 1024 * sizeof(float);
  int*   samples  = (int*)w;   w += 8192 * sizeof(int);
  int*   choice   = (int*)w;   w += 8192 * sizeof(int);
  float* scores   = (float*)w; w += 128 * sizeof(float);

  // large scratch lives inside d_out (rewritten by k_out at the end):
  // Eall: 16*64*8*256 = 2,097,152 floats (chosen slots only)
  float* Eall = out;

  // keys = jax.random.split(jax.random.key(42), 8) under PARTITIONABLE
  Keys16 keys;
  for (uint32_t i = 0; i < 8; ++i) {
    uint32_t a, bq;
    tf2x32(0u, 42u, 0u, i, &a, &bq);
    keys.k[2 * i] = a; keys.k[2 * i + 1] = bq;
  }

  k_topk<<<1024, 256, 0, stream>>>(probas, mask, topk_idx, logits, S);
  k_sample<<<32, 256, 0, stream>>>(keys, mask, topk_idx, logits, samples, choice);
  k_ce<<<1024, 256, 0, stream>>>(topk_idx, bvoc, emb, W1, h_d, b1, mask, choice,
                                 Eall);
  k_gram<<<128, 256, 0, stream>>>(Eall, mask, choice, scores);
  k_out<<<1024, 256, 0, stream>>>(probas, mask, samples, topk_idx, scores, S,
                                  out, out + 16777216);
}